// Round 6
// baseline (804.327 us; speedup 1.0000x reference)
//
#include <hip/hip_runtime.h>
#include <hip/hip_bf16.h>
#include <stdint.h>

typedef unsigned int u32;
typedef unsigned short u16;
typedef short short8 __attribute__((ext_vector_type(8)));
typedef float f32x4 __attribute__((ext_vector_type(4)));

#define NN 50000
#define NE 200000
#define WCT 576     // 256 fsrc | 256 res | 8 e_src | 8 e_dst | 48 pad (cols of C)

__device__ __forceinline__ float leaky(float x){ return x >= 0.f ? x : 0.2f*x; }
__device__ __forceinline__ float bf2f(u16 u){ return __uint_as_float(((u32)u)<<16); }
__device__ __forceinline__ u16 f2bf(float f){            // RNE
    u32 u = __float_as_uint(f);
    u32 r = (u + 0x7fffu + ((u>>16)&1u)) >> 16;
    return (u16)r;
}
// pack 2 floats -> 2 bf16 (truncation) in ONE v_perm_b32
__device__ __forceinline__ u32 pack_bf2(float a, float b){
    return __builtin_amdgcn_perm(__float_as_uint(b), __float_as_uint(a), 0x07060302u);
}
__device__ __forceinline__ int nt_src(int r){ return (r==0)?0:((r==3)?2:1); }
__device__ __forceinline__ int nt_dst(int r){ return (r==1)?0:((r==2)?2:1); }

// ra[r][512] = rel_emb[r] @ rel_W[r]
__global__ void k_ra(const float* __restrict__ rel_emb, const float* __restrict__ rel_W,
                     float* __restrict__ ra){
    int r = blockIdx.x;
    for (int j = threadIdx.x; j < 512; j += blockDim.x){
        float acc = 0.f;
        for (int i = 0; i < 64; i++) acc += rel_emb[r*64+i] * rel_W[(r*64+i)*512 + j];
        ra[r*512 + j] = acc;
    }
}

// Assemble WcatT[r] (576 x 256, bf16, transposed so B-frag reads are K-contiguous)
__global__ void k_wcat(const float* __restrict__ node_W, const float* __restrict__ res_W,
                       const float* __restrict__ ra, u16* __restrict__ WcatT){
    int g = blockIdx.x*blockDim.x + threadIdx.x;
    if (g >= 4*WCT*256) return;
    int r = g/(WCT*256); int rem = g%(WCT*256); int n = rem/256; int k = rem%256;
    int s = nt_src(r), d = nt_dst(r);
    float v;
    if (n < 256) v = node_W[(s*256+k)*256 + n];
    else if (n < 512) v = res_W[(d*256+k)*256 + (n-256)];
    else if (n < 520){ // e_src weights: node_W[s]·ra[h, D:]
        int h = n-512; float a = 0.f;
        for (int dd = 0; dd < 32; dd++) a += node_W[(s*256+k)*256 + h*32+dd] * ra[r*512 + h*64+32+dd];
        v = a;
    } else if (n < 528){ // e_dst weights: node_W[d]·ra[h, :D]
        int h = n-520; float a = 0.f;
        for (int dd = 0; dd < 32; dd++) a += node_W[(d*256+k)*256 + h*32+dd] * ra[r*512 + h*64+dd];
        v = a;
    } else v = 0.f;
    WcatT[(size_t)(r*WCT+n)*256 + k] = f2bf(v);
}

// MFMA GEMM, fat blocks: one block = 64-row strip x ALL 576 N.
// A fragments K-resident in registers (loaded once from HBM, fp32->bf16 packed).
// B streamed per 64-col n-tile through LDS with register prefetch.
// 4 waves 2x2 over 64x64; epilogue LDS-staged, dwordx4 line-complete stores.
__launch_bounds__(256)
__global__ void k_gemm(const float* __restrict__ feat, const u16* __restrict__ WcatT,
                       const float* __restrict__ res_b,
                       u16* __restrict__ fsrc, u16* __restrict__ resb,
                       float* __restrict__ e_comb){
    __shared__ uint4 lsB[2048];          // 64 n-rows x 32 chunks(16B) = 32 KB
    __shared__ u16  cst[64*72];          // 9.2 KB epilogue C-stage, stride 72
    const short8* lsB8 = (const short8*)lsB;

    int r = blockIdx.y;
    int row0 = blockIdx.x*64;
    const float* A = feat + (size_t)r*NN*256;
    const u16*   W = WcatT + (size_t)r*WCT*256;

    int t = threadIdx.x;
    int w = t>>6, l = t&63;
    int wm = (w>>1)*32, wn = (w&1)*32;
    int li = l & 15, lg = l >> 4;

    // ---- A fragments: direct global -> registers, K-resident (64 VGPR/lane)
    short8 afr[2][8];
    #pragma unroll
    for (int mt = 0; mt < 2; mt++){
        int grow = row0 + wm + mt*16 + li; if (grow > NN-1) grow = NN-1;
        const float* ap = A + (size_t)grow*256 + lg*8;
        #pragma unroll
        for (int kk = 0; kk < 8; kk++){
            float4 x = *(const float4*)(ap + kk*32);
            float4 y = *(const float4*)(ap + kk*32 + 4);
            short8 f;
            ((u32*)&f)[0] = pack_bf2(x.x, x.y);
            ((u32*)&f)[1] = pack_bf2(x.z, x.w);
            ((u32*)&f)[2] = pack_bf2(y.x, y.y);
            ((u32*)&f)[3] = pack_bf2(y.z, y.w);
            afr[mt][kk] = f;
        }
    }

    // ---- B staging indices: thread t -> n-row t>>2, quarter (t&3) of 32 chunks
    int brow = t>>2, bq = t&3;
    const u16* bbase = W + (size_t)brow*256 + bq*64;   // + n0*256 per tile
    uint4 bv[8];
    #pragma unroll
    for (int i = 0; i < 8; i++) bv[i] = ((const uint4*)bbase)[i];   // tile 0

    int d = nt_dst(r);
    int orow = t>>2, oq = t&3;
    int ogrow = row0 + orow;
    size_t onidx = (size_t)r*NN + ogrow;

    for (int nt9 = 0; nt9 < 8; nt9++){
        // stage B (prev tile's LDS readers done via prev epilogue sync)
        #pragma unroll
        for (int i = 0; i < 8; i++)
            lsB[brow*32 + ((bq*8+i) ^ (brow&7))] = bv[i];
        __syncthreads();
        // prefetch next B tile (nt9+1 <= 8) while computing this one
        {
            const uint4* nb = (const uint4*)(bbase + (size_t)(nt9+1)*64*256);
            #pragma unroll
            for (int i = 0; i < 8; i++) bv[i] = nb[i];
        }
        // MFMA: 32 per wave
        f32x4 acc[2][2] = {};
        #pragma unroll
        for (int kk = 0; kk < 8; kk++){
            short8 bfr[2];
            #pragma unroll
            for (int nt = 0; nt < 2; nt++){
                int nrow = wn + nt*16 + li;
                bfr[nt] = lsB8[nrow*32 + ((kk*4+lg) ^ (nrow&7))];
            }
            #pragma unroll
            for (int mt = 0; mt < 2; mt++)
                #pragma unroll
                for (int nt = 0; nt < 2; nt++)
                    acc[mt][nt] = __builtin_amdgcn_mfma_f32_16x16x32_bf16(afr[mt][kk], bfr[nt], acc[mt][nt], 0,0,0);
        }
        // epilogue: stage to LDS (bf16), then line-complete dwordx4 stores
        float bias[2] = {0.f, 0.f};
        if (nt9 >= 4){
            bias[0] = res_b[d*256 + (nt9-4)*64 + wn + li];
            bias[1] = res_b[d*256 + (nt9-4)*64 + wn + 16 + li];
        }
        #pragma unroll
        for (int mt = 0; mt < 2; mt++)
            #pragma unroll
            for (int nt = 0; nt < 2; nt++)
                #pragma unroll
                for (int qq = 0; qq < 4; qq++)
                    cst[(wm + mt*16 + lg*4 + qq)*72 + wn + nt*16 + li] = f2bf(acc[mt][nt][qq] + bias[nt]);
        __syncthreads();
        if (ogrow < NN){
            u16* dst = (nt9 < 4) ? (fsrc + onidx*256 + nt9*64) : (resb + onidx*256 + (nt9-4)*64);
            const uint4* src = (const uint4*)(cst + orow*72 + oq*16);
            uint4* dq = (uint4*)(dst + oq*16);
            dq[0] = src[0];
            dq[1] = src[1];
        }
        __syncthreads();   // cst reads done before next iteration's epi overwrites
    }

    // ---- tile 8: e-columns 512..527 -> e_comb (direct stores, 64B lines)
    #pragma unroll
    for (int i = 0; i < 8; i++)
        lsB[brow*32 + ((bq*8+i) ^ (brow&7))] = bv[i];
    __syncthreads();
    f32x4 acc[2] = {};
    #pragma unroll
    for (int kk = 0; kk < 8; kk++){
        int nrow = li;                       // wn==0, nt==0 only
        short8 bfr = lsB8[nrow*32 + ((kk*4+lg) ^ (nrow&7))];
        #pragma unroll
        for (int mt = 0; mt < 2; mt++)
            acc[mt] = __builtin_amdgcn_mfma_f32_16x16x32_bf16(afr[mt][kk], bfr, acc[mt], 0,0,0);
    }
    if (wn == 0){
        #pragma unroll
        for (int mt = 0; mt < 2; mt++)
            #pragma unroll
            for (int qq = 0; qq < 4; qq++){
                int row = row0 + wm + mt*16 + lg*4 + qq;
                if (row < NN)
                    e_comb[((size_t)r*NN + row)*16 + li] = acc[mt][qq];
            }
    }
}

// ---- CSR build: count -> hierarchical scan -> scatter ----

__global__ void k_count(const int* __restrict__ dst_idx, u32* __restrict__ cnt){
    int r = blockIdx.y; int e = blockIdx.x*256 + threadIdx.x;
    if (e >= NE) return;
    atomicAdd(&cnt[r*NN + dst_idx[r*NE+e]], 1u);
}

__global__ void k_scan1(const u32* __restrict__ cnt, u32* __restrict__ bsum){
    int r = blockIdx.y, b = blockIdx.x;
    int i = b*256 + threadIdx.x;
    u32 v = (i < NN) ? cnt[r*NN+i] : 0u;
    #pragma unroll
    for (int off = 1; off < 64; off <<= 1) v += __shfl_xor(v, off, 64);
    __shared__ u32 wsum[4];
    int lane = threadIdx.x & 63, w = threadIdx.x >> 6;
    if (lane == 0) wsum[w] = v;
    __syncthreads();
    if (threadIdx.x == 0) bsum[r*256 + b] = wsum[0]+wsum[1]+wsum[2]+wsum[3];
}

__device__ __forceinline__ u32 block_scan_incl(u32 v){
    __shared__ u32 wsum[4];
    int lane = threadIdx.x & 63, w = threadIdx.x >> 6;
    #pragma unroll
    for (int off = 1; off < 64; off <<= 1){
        u32 t = __shfl_up(v, off, 64);
        if (lane >= off) v += t;
    }
    if (lane == 63) wsum[w] = v;
    __syncthreads();
    u32 add = 0;
    #pragma unroll
    for (int k = 0; k < 4; k++) if (k < w) add += wsum[k];
    return v + add;
}

__global__ void k_scan2(u32* __restrict__ bsum){
    int r = blockIdx.x;
    u32 v = bsum[r*256 + threadIdx.x];
    u32 incl = block_scan_incl(v);
    bsum[r*256 + threadIdx.x] = incl - v;
}

__global__ void k_scan3(const u32* __restrict__ cnt, const u32* __restrict__ bsum,
                        u32* __restrict__ row_ptr){
    int r = blockIdx.y, b = blockIdx.x;
    int i = b*256 + threadIdx.x;
    u32 v = (i < NN) ? cnt[r*NN+i] : 0u;
    u32 incl = block_scan_incl(v);
    if (i < NN) row_ptr[r*(NN+1) + i + 1] = bsum[r*256 + b] + incl;
    if (b == 0 && threadIdx.x == 0) row_ptr[r*(NN+1)] = 0u;
}

__global__ void k_scatter(const int* __restrict__ src_idx, const int* __restrict__ dst_idx,
                          const float* __restrict__ e_comb,
                          const u32* __restrict__ row_ptr, u32* __restrict__ cnt2,
                          u32* __restrict__ src_pack, float* __restrict__ e_pack){
    int r = blockIdx.y; int e = blockIdx.x*256 + threadIdx.x;
    if (e >= NE) return;
    int s = src_idx[r*NE+e], d = dst_idx[r*NE+e];
    u32 pos = row_ptr[r*(NN+1)+d] + atomicAdd(&cnt2[r*NN+d], 1u);
    src_pack[r*NE + pos] = (u32)s;
    const float* es = e_comb + (size_t)(r*NN+s)*16;
    const float* ed = e_comb + (size_t)(r*NN+d)*16 + 8;
    float* ep = e_pack + ((size_t)(r*NE)+pos)*8;
    #pragma unroll
    for (int h = 0; h < 8; h++) ep[h] = leaky(es[h] + ed[h]);
}

// one wave per (node, rel): inline segment softmax + aggregation + relu + residual gate.
__launch_bounds__(256)
__global__ void k_agg(const u32* __restrict__ row_ptr, const u32* __restrict__ src_pack,
                      const float* __restrict__ e_pack, const u16* __restrict__ fsrc,
                      const u16* __restrict__ resb, const float* __restrict__ res_alpha,
                      float* __restrict__ out){
    int r = blockIdx.y;
    int wid = threadIdx.x >> 6;
    int n = blockIdx.x*4 + wid;
    if (n >= NN) return;
    int l = threadIdx.x & 63;
    u32 p0 = row_ptr[r*(NN+1)+n];
    u32 p1 = row_ptr[r*(NN+1)+n+1];
    int deg = (int)(p1 - p0);

    float m = -1e30f, s = 0.f;
    for (int i = (l>>3); i < deg; i += 8){
        float e = e_pack[((size_t)(r*NE) + p0 + i)*8 + (l&7)];
        float mn = fmaxf(m, e);
        s = s*__expf(m - mn) + __expf(e - mn);
        m = mn;
    }
    #pragma unroll
    for (int msk = 8; msk < 64; msk <<= 1){
        float m2 = __shfl_xor(m, msk, 64);
        float s2 = __shfl_xor(s, msk, 64);
        float mn = fmaxf(m, m2);
        s = s*__expf(m - mn) + s2*__expf(m2 - mn);
        m = mn;
    }
    int h = l >> 3;
    float mh = __shfl(m, h, 64);
    float sh = __shfl(s, h, 64);

    float a0=0.f, a1=0.f, a2=0.f, a3=0.f;
    for (int i = 0; i < deg; i++){
        size_t ep = (size_t)(r*NE) + p0 + i;
        float a = __expf(e_pack[ep*8 + h] - mh) / sh;
        u32 src = src_pack[ep];
        ushort4 f = *(const ushort4*)(fsrc + ((size_t)r*NN+src)*256 + l*4);
        a0 += bf2f(f.x)*a; a1 += bf2f(f.y)*a; a2 += bf2f(f.z)*a; a3 += bf2f(f.w)*a;
    }
    int d = nt_dst(r);
    float alpha = 1.f/(1.f + __expf(-res_alpha[d]));
    float beta = 1.f - alpha;
    ushort4 rv = *(const ushort4*)(resb + ((size_t)r*NN+n)*256 + l*4);
    float4 o;
    o.x = fmaxf(a0,0.f)*alpha + bf2f(rv.x)*beta;
    o.y = fmaxf(a1,0.f)*alpha + bf2f(rv.y)*beta;
    o.z = fmaxf(a2,0.f)*alpha + bf2f(rv.z)*beta;
    o.w = fmaxf(a3,0.f)*alpha + bf2f(rv.w)*beta;
    *(float4*)(out + ((size_t)r*NN+n)*256 + l*4) = o;
}

__global__ void k_cross(float* __restrict__ out, const float* __restrict__ cross_attn){
    int n = blockIdx.x; int t = threadIdx.x;   // t = h*32 + d
    size_t i0 = (size_t)n*256 + t;
    size_t i3 = (size_t)3*NN*256 + (size_t)n*256 + t;
    float v0 = out[i0], v3 = out[i3];
    float ca0 = cross_attn[t];
    float ca3 = cross_attn[3*256 + t];
    float p00 = v0*ca0, p30 = v3*ca0, p03 = v0*ca3, p33 = v3*ca3;
    #pragma unroll
    for (int m = 16; m >= 1; m >>= 1){
        p00 += __shfl_xor(p00, m, 64);
        p30 += __shfl_xor(p30, m, 64);
        p03 += __shfl_xor(p03, m, 64);
        p33 += __shfl_xor(p33, m, 64);
    }
    float l0 = leaky(p00), l3 = leaky(p30);
    float mm = fmaxf(l0, l3);
    float w0 = __expf(l0-mm), w3 = __expf(l3-mm);
    float o0 = (w0*v0 + w3*v3) / (w0+w3);
    float q0 = leaky(p03), q3 = leaky(p33);
    float mq = fmaxf(q0, q3);
    float u0 = __expf(q0-mq), u3 = __expf(q3-mq);
    float o3 = (u0*v0 + u3*v3) / (u0+u3);
    out[i0] = o0; out[i3] = o3;
}

__global__ void k_relout(const float* __restrict__ rel_emb, const float* __restrict__ prop_W,
                         const float* __restrict__ prop_b, float* __restrict__ out){
    int r = blockIdx.x; int o = threadIdx.x;
    float acc = prop_b[r*256 + o];
    for (int i = 0; i < 64; i++) acc += rel_emb[r*64+i] * prop_W[(r*64+i)*256 + o];
    out[(size_t)4*NN*256 + r*256 + o] = acc;
}

extern "C" void kernel_launch(void* const* d_in, const int* in_sizes, int n_in,
                              void* d_out, int out_size, void* d_ws, size_t ws_size,
                              hipStream_t stream){
    const float* feat      = (const float*)d_in[0];
    const float* rel_emb   = (const float*)d_in[1];
    const float* node_W    = (const float*)d_in[2];
    const float* rel_W     = (const float*)d_in[3];
    const float* res_W     = (const float*)d_in[4];
    const float* res_b     = (const float*)d_in[5];
    const float* res_alpha = (const float*)d_in[6];
    const float* cross_attn= (const float*)d_in[7];
    const float* prop_W    = (const float*)d_in[8];
    const float* prop_b    = (const float*)d_in[9];
    const int* src_idx     = (const int*)d_in[10];
    const int* dst_idx     = (const int*)d_in[11];
    float* out = (float*)d_out;

    char* ws = (char*)d_ws;
    u32*   cnt     = (u32*)  (ws);                 //    800,000 B (4,NN)
    u32*   cnt2    = (u32*)  (ws + 800000);        //    800,000 B (4,NN)
    u32*   bsum    = (u32*)  (ws + 1600000);       //      4,096 B (4,256)
    u32*   row_ptr = (u32*)  (ws + 1604096);       //    800,016 B (4,NN+1)
    float* ra      = (float*)(ws + 2404112);       //      8,192 B (4,512)
    u16*   WcatT   = (u16*)  (ws + 2412304);       //  1,179,648 B (4,576,256) bf16
    float* e_comb  = (float*)(ws + 3591952);       // 12,800,000 B (4,NN,16) [src|dst]
    u32*   src_pack= (u32*)  (ws + 16391952);      //  3,200,000 B (4,NE)
    float* e_pack  = (float*)(ws + 19591952);      // 25,600,000 B (4,NE,8)
    u16*   fsrc    = (u16*)  (ws + 45191952);      //102,400,000 B (4,NN,256) bf16
    u16*   resb    = (u16*)  (ws + 147591952);     //102,400,000 B (4,NN,256) bf16
    // total: 249,991,952 B

    hipMemsetAsync(cnt, 0, 1604096, stream);  // cnt + cnt2 + bsum

    k_ra<<<4, 256, 0, stream>>>(rel_emb, rel_W, ra);
    k_wcat<<<(4*WCT*256)/256, 256, 0, stream>>>(node_W, res_W, ra, WcatT);
    dim3 gg((NN+63)/64, 4);
    k_gemm<<<gg, 256, 0, stream>>>(feat, WcatT, res_b, fsrc, resb, e_comb);

    dim3 geg((NE+255)/256, 4);
    k_count<<<geg, 256, 0, stream>>>(dst_idx, cnt);
    dim3 gsc((NN+255)/256, 4);
    k_scan1<<<gsc, 256, 0, stream>>>(cnt, bsum);
    k_scan2<<<4, 256, 0, stream>>>(bsum);
    k_scan3<<<gsc, 256, 0, stream>>>(cnt, bsum, row_ptr);
    k_scatter<<<geg, 256, 0, stream>>>(src_idx, dst_idx, e_comb, row_ptr, cnt2,
                                       src_pack, e_pack);
    dim3 ga((NN+3)/4, 4);
    k_agg<<<ga, 256, 0, stream>>>(row_ptr, src_pack, e_pack, fsrc, resb, res_alpha, out);

    k_cross<<<NN, 256, 0, stream>>>(out, cross_attn);
    k_relout<<<4, 256, 0, stream>>>(rel_emb, prop_W, prop_b, out);
}

// Round 7
// 551.488 us; speedup vs baseline: 1.4585x; 1.4585x over previous
//
#include <hip/hip_runtime.h>
#include <hip/hip_bf16.h>
#include <stdint.h>

typedef unsigned int u32;
typedef unsigned short u16;
typedef short short8 __attribute__((ext_vector_type(8)));
typedef float f32x4 __attribute__((ext_vector_type(4)));
typedef __attribute__((address_space(1))) const u32 gu32;
typedef __attribute__((address_space(3))) u32 lu32;

#define NN 50000
#define NE 200000
#define WCT 576     // 256 fsrc | 256 res | 8 e_src | 8 e_dst | 48 pad (cols of C)

__device__ __forceinline__ float leaky(float x){ return x >= 0.f ? x : 0.2f*x; }
__device__ __forceinline__ float bf2f(u16 u){ return __uint_as_float(((u32)u)<<16); }
__device__ __forceinline__ u16 f2bf(float f){            // RNE
    u32 u = __float_as_uint(f);
    u32 r = (u + 0x7fffu + ((u>>16)&1u)) >> 16;
    return (u16)r;
}
// pack 2 floats -> 2 bf16 (truncation) in ONE v_perm_b32
__device__ __forceinline__ u32 pack_bf2(float a, float b){
    return __builtin_amdgcn_perm(__float_as_uint(b), __float_as_uint(a), 0x07060302u);
}
__device__ __forceinline__ int nt_src(int r){ return (r==0)?0:((r==3)?2:1); }
__device__ __forceinline__ int nt_dst(int r){ return (r==1)?0:((r==2)?2:1); }

// ra[r][512] = rel_emb[r] @ rel_W[r]
__global__ void k_ra(const float* __restrict__ rel_emb, const float* __restrict__ rel_W,
                     float* __restrict__ ra){
    int r = blockIdx.x;
    for (int j = threadIdx.x; j < 512; j += blockDim.x){
        float acc = 0.f;
        for (int i = 0; i < 64; i++) acc += rel_emb[r*64+i] * rel_W[(r*64+i)*512 + j];
        ra[r*512 + j] = acc;
    }
}

// Assemble WcatS: chunk-transposed bf16 layout matching linear global_load_lds staging:
//   WcatS[((r*9+tile)*32 + kc)*512 + nrow*8 + off] = W^T[n=tile*64+nrow][k=kc*8+off]
// so LDS chunk (kc*64+nrow) holds B[n][k-chunk kc] and ds_reads are 2-way-conflict-free.
__global__ void k_wcat(const float* __restrict__ node_W, const float* __restrict__ res_W,
                       const float* __restrict__ ra, u16* __restrict__ WcatS){
    int g = blockIdx.x*blockDim.x + threadIdx.x;
    if (g >= 4*WCT*256) return;
    int r = g/147456; int rem = g%147456;
    int tile = rem/16384; int rem2 = rem%16384;
    int kc = rem2/512; int rem3 = rem2%512;
    int nrow = rem3>>3; int off = rem3&7;
    int n = tile*64 + nrow;
    int k = kc*8 + off;
    int s = nt_src(r), d = nt_dst(r);
    float v;
    if (n < 256) v = node_W[(s*256+k)*256 + n];
    else if (n < 512) v = res_W[(d*256+k)*256 + (n-256)];
    else if (n < 520){ // e_src weights: node_W[s]·ra[h, D:]
        int h = n-512; float a = 0.f;
        for (int dd = 0; dd < 32; dd++) a += node_W[(s*256+k)*256 + h*32+dd] * ra[r*512 + h*64+32+dd];
        v = a;
    } else if (n < 528){ // e_dst weights: node_W[d]·ra[h, :D]
        int h = n-520; float a = 0.f;
        for (int dd = 0; dd < 32; dd++) a += node_W[(d*256+k)*256 + h*32+dd] * ra[r*512 + h*64+dd];
        v = a;
    } else v = 0.f;
    WcatS[g] = f2bf(v);
}

// MFMA GEMM, fat blocks: one block = 64-row strip x ALL 576 N.
// A K-resident in registers (HBM once, fp32->bf16 v_perm pack).
// B async-staged via global_load_lds into 2x32KB LDS double buffer (T14):
// issue at tile start, drain at post-compute __syncthreads.
__launch_bounds__(256)
__global__ void k_gemm(const float* __restrict__ feat, const u16* __restrict__ WcatS,
                       const float* __restrict__ res_b,
                       u16* __restrict__ fsrc, u16* __restrict__ resb,
                       float* __restrict__ e_comb){
    __shared__ uint4 lsB[4096];          // 2 x 32KB B double buffer
    __shared__ u16  cst[64*72];          // 9.2 KB epilogue C-stage, stride 72
    const short8* lsB8 = (const short8*)lsB;

    int r = blockIdx.y;
    int row0 = blockIdx.x*64;
    const float* A = feat + (size_t)r*NN*256;
    const u16*   W = WcatS + (size_t)r*9*16384;

    int t = threadIdx.x;
    int w = t>>6, l = t&63;
    int wm = (w>>1)*32, wn = (w&1)*32;
    int li = l & 15, lg = l >> 4;

    // ---- A fragments: direct global -> registers, K-resident (64 VGPR/lane)
    short8 afr[2][8];
    #pragma unroll
    for (int mt = 0; mt < 2; mt++){
        int grow = row0 + wm + mt*16 + li; if (grow > NN-1) grow = NN-1;
        const float* ap = A + (size_t)grow*256 + lg*8;
        #pragma unroll
        for (int kk = 0; kk < 8; kk++){
            float4 x = *(const float4*)(ap + kk*32);
            float4 y = *(const float4*)(ap + kk*32 + 4);
            short8 f;
            ((u32*)&f)[0] = pack_bf2(x.x, x.y);
            ((u32*)&f)[1] = pack_bf2(x.z, x.w);
            ((u32*)&f)[2] = pack_bf2(y.x, y.y);
            ((u32*)&f)[3] = pack_bf2(y.z, y.w);
            afr[mt][kk] = f;
        }
    }

    // ---- prologue: stage tile 0 into buf 0 (async direct-to-LDS)
    #pragma unroll
    for (int i = 0; i < 8; i++){
        int chunk = w*512 + i*64 + l;
        __builtin_amdgcn_global_load_lds((gu32*)(W + (size_t)chunk*8),
                                         (lu32*)((char*)lsB + (w*512 + i*64)*16), 16, 0, 0);
    }
    __syncthreads();

    int d = nt_dst(r);
    int orow = t>>2, oq = t&3;
    int ogrow = row0 + orow;
    size_t onidx = (size_t)r*NN + ogrow;

    for (int T = 0; T < 8; T++){
        int cur = T & 1;
        // issue async stage of tile T+1 into the other buffer (flies under MFMA)
        {
            const u16* tb = W + (size_t)(T+1)*16384;
            char* lb = (char*)lsB + (cur^1)*32768;
            #pragma unroll
            for (int i = 0; i < 8; i++){
                int chunk = w*512 + i*64 + l;
                __builtin_amdgcn_global_load_lds((gu32*)(tb + (size_t)chunk*8),
                                                 (lu32*)(lb + (w*512 + i*64)*16), 16, 0, 0);
            }
        }
        // compute tile T from buf[cur]
        f32x4 acc[2][2] = {};
        #pragma unroll
        for (int kk = 0; kk < 8; kk++){
            short8 bfr[2];
            #pragma unroll
            for (int nt = 0; nt < 2; nt++)
                bfr[nt] = lsB8[cur*2048 + (kk*4+lg)*64 + wn + nt*16 + li];
            #pragma unroll
            for (int mt = 0; mt < 2; mt++)
                #pragma unroll
                for (int nt = 0; nt < 2; nt++)
                    acc[mt][nt] = __builtin_amdgcn_mfma_f32_16x16x32_bf16(afr[mt][kk], bfr[nt], acc[mt][nt], 0,0,0);
        }
        // epilogue: stage to LDS (bf16), then line-complete dwordx4 stores
        float bias[2] = {0.f, 0.f};
        if (T >= 4){
            bias[0] = res_b[d*256 + (T-4)*64 + wn + li];
            bias[1] = res_b[d*256 + (T-4)*64 + wn + 16 + li];
        }
        #pragma unroll
        for (int mt = 0; mt < 2; mt++)
            #pragma unroll
            for (int nt = 0; nt < 2; nt++)
                #pragma unroll
                for (int qq = 0; qq < 4; qq++)
                    cst[(wm + mt*16 + lg*4 + qq)*72 + wn + nt*16 + li] = f2bf(acc[mt][nt][qq] + bias[nt]);
        __syncthreads();   // cst visible; also drains this wave's async loads (all waves => tile T+1 ready after barrier)
        if (ogrow < NN){
            u16* dst = (T < 4) ? (fsrc + onidx*256 + T*64) : (resb + onidx*256 + (T-4)*64);
            const uint4* src = (const uint4*)(cst + orow*72 + oq*16);
            uint4* dq = (uint4*)(dst + oq*16);
            dq[0] = src[0];
            dq[1] = src[1];
        }
        __syncthreads();   // cst reads done before next iteration overwrites
    }

    // ---- tile 8: e-columns 512..527 (nrow 0..15 of tile 8, in buf 0) -> e_comb
    if (wn == 0){
        f32x4 acc[2] = {};
        #pragma unroll
        for (int kk = 0; kk < 8; kk++){
            short8 bfr = lsB8[(kk*4+lg)*64 + li];
            #pragma unroll
            for (int mt = 0; mt < 2; mt++)
                acc[mt] = __builtin_amdgcn_mfma_f32_16x16x32_bf16(afr[mt][kk], bfr, acc[mt], 0,0,0);
        }
        #pragma unroll
        for (int mt = 0; mt < 2; mt++)
            #pragma unroll
            for (int qq = 0; qq < 4; qq++){
                int row = row0 + wm + mt*16 + lg*4 + qq;
                if (row < NN)
                    e_comb[((size_t)r*NN + row)*16 + li] = acc[mt][qq];
            }
    }
}

// ---- CSR build: count -> hierarchical scan -> scatter ----

__global__ void k_count(const int* __restrict__ dst_idx, u32* __restrict__ cnt){
    int r = blockIdx.y; int e = blockIdx.x*256 + threadIdx.x;
    if (e >= NE) return;
    atomicAdd(&cnt[r*NN + dst_idx[r*NE+e]], 1u);
}

__global__ void k_scan1(const u32* __restrict__ cnt, u32* __restrict__ bsum){
    int r = blockIdx.y, b = blockIdx.x;
    int i = b*256 + threadIdx.x;
    u32 v = (i < NN) ? cnt[r*NN+i] : 0u;
    #pragma unroll
    for (int off = 1; off < 64; off <<= 1) v += __shfl_xor(v, off, 64);
    __shared__ u32 wsum[4];
    int lane = threadIdx.x & 63, w = threadIdx.x >> 6;
    if (lane == 0) wsum[w] = v;
    __syncthreads();
    if (threadIdx.x == 0) bsum[r*256 + b] = wsum[0]+wsum[1]+wsum[2]+wsum[3];
}

__device__ __forceinline__ u32 block_scan_incl(u32 v){
    __shared__ u32 wsum[4];
    int lane = threadIdx.x & 63, w = threadIdx.x >> 6;
    #pragma unroll
    for (int off = 1; off < 64; off <<= 1){
        u32 t = __shfl_up(v, off, 64);
        if (lane >= off) v += t;
    }
    if (lane == 63) wsum[w] = v;
    __syncthreads();
    u32 add = 0;
    #pragma unroll
    for (int k = 0; k < 4; k++) if (k < w) add += wsum[k];
    return v + add;
}

__global__ void k_scan2(u32* __restrict__ bsum){
    int r = blockIdx.x;
    u32 v = bsum[r*256 + threadIdx.x];
    u32 incl = block_scan_incl(v);
    bsum[r*256 + threadIdx.x] = incl - v;
}

__global__ void k_scan3(const u32* __restrict__ cnt, const u32* __restrict__ bsum,
                        u32* __restrict__ row_ptr){
    int r = blockIdx.y, b = blockIdx.x;
    int i = b*256 + threadIdx.x;
    u32 v = (i < NN) ? cnt[r*NN+i] : 0u;
    u32 incl = block_scan_incl(v);
    if (i < NN) row_ptr[r*(NN+1) + i + 1] = bsum[r*256 + b] + incl;
    if (b == 0 && threadIdx.x == 0) row_ptr[r*(NN+1)] = 0u;
}

__global__ void k_scatter(const int* __restrict__ src_idx, const int* __restrict__ dst_idx,
                          const float* __restrict__ e_comb,
                          const u32* __restrict__ row_ptr, u32* __restrict__ cnt2,
                          u32* __restrict__ src_pack, float* __restrict__ e_pack){
    int r = blockIdx.y; int e = blockIdx.x*256 + threadIdx.x;
    if (e >= NE) return;
    int s = src_idx[r*NE+e], d = dst_idx[r*NE+e];
    u32 pos = row_ptr[r*(NN+1)+d] + atomicAdd(&cnt2[r*NN+d], 1u);
    src_pack[r*NE + pos] = (u32)s;
    const float* es = e_comb + (size_t)(r*NN+s)*16;
    const float* ed = e_comb + (size_t)(r*NN+d)*16 + 8;
    float* ep = e_pack + ((size_t)(r*NE)+pos)*8;
    #pragma unroll
    for (int h = 0; h < 8; h++) ep[h] = leaky(es[h] + ed[h]);
}

// one wave per (node, rel): inline segment softmax + aggregation + relu + residual gate.
__launch_bounds__(256)
__global__ void k_agg(const u32* __restrict__ row_ptr, const u32* __restrict__ src_pack,
                      const float* __restrict__ e_pack, const u16* __restrict__ fsrc,
                      const u16* __restrict__ resb, const float* __restrict__ res_alpha,
                      float* __restrict__ out){
    int r = blockIdx.y;
    int wid = threadIdx.x >> 6;
    int n = blockIdx.x*4 + wid;
    if (n >= NN) return;
    int l = threadIdx.x & 63;
    u32 p0 = row_ptr[r*(NN+1)+n];
    u32 p1 = row_ptr[r*(NN+1)+n+1];
    int deg = (int)(p1 - p0);

    float m = -1e30f, s = 0.f;
    for (int i = (l>>3); i < deg; i += 8){
        float e = e_pack[((size_t)(r*NE) + p0 + i)*8 + (l&7)];
        float mn = fmaxf(m, e);
        s = s*__expf(m - mn) + __expf(e - mn);
        m = mn;
    }
    #pragma unroll
    for (int msk = 8; msk < 64; msk <<= 1){
        float m2 = __shfl_xor(m, msk, 64);
        float s2 = __shfl_xor(s, msk, 64);
        float mn = fmaxf(m, m2);
        s = s*__expf(m - mn) + s2*__expf(m2 - mn);
        m = mn;
    }
    int h = l >> 3;
    float mh = __shfl(m, h, 64);
    float sh = __shfl(s, h, 64);

    float a0=0.f, a1=0.f, a2=0.f, a3=0.f;
    for (int i = 0; i < deg; i++){
        size_t ep = (size_t)(r*NE) + p0 + i;
        float a = __expf(e_pack[ep*8 + h] - mh) / sh;
        u32 src = src_pack[ep];
        ushort4 f = *(const ushort4*)(fsrc + ((size_t)r*NN+src)*256 + l*4);
        a0 += bf2f(f.x)*a; a1 += bf2f(f.y)*a; a2 += bf2f(f.z)*a; a3 += bf2f(f.w)*a;
    }
    int d = nt_dst(r);
    float alpha = 1.f/(1.f + __expf(-res_alpha[d]));
    float beta = 1.f - alpha;
    ushort4 rv = *(const ushort4*)(resb + ((size_t)r*NN+n)*256 + l*4);
    float4 o;
    o.x = fmaxf(a0,0.f)*alpha + bf2f(rv.x)*beta;
    o.y = fmaxf(a1,0.f)*alpha + bf2f(rv.y)*beta;
    o.z = fmaxf(a2,0.f)*alpha + bf2f(rv.z)*beta;
    o.w = fmaxf(a3,0.f)*alpha + bf2f(rv.w)*beta;
    *(float4*)(out + ((size_t)r*NN+n)*256 + l*4) = o;
}

__global__ void k_cross(float* __restrict__ out, const float* __restrict__ cross_attn){
    int n = blockIdx.x; int t = threadIdx.x;   // t = h*32 + d
    size_t i0 = (size_t)n*256 + t;
    size_t i3 = (size_t)3*NN*256 + (size_t)n*256 + t;
    float v0 = out[i0], v3 = out[i3];
    float ca0 = cross_attn[t];
    float ca3 = cross_attn[3*256 + t];
    float p00 = v0*ca0, p30 = v3*ca0, p03 = v0*ca3, p33 = v3*ca3;
    #pragma unroll
    for (int m = 16; m >= 1; m >>= 1){
        p00 += __shfl_xor(p00, m, 64);
        p30 += __shfl_xor(p30, m, 64);
        p03 += __shfl_xor(p03, m, 64);
        p33 += __shfl_xor(p33, m, 64);
    }
    float l0 = leaky(p00), l3 = leaky(p30);
    float mm = fmaxf(l0, l3);
    float w0 = __expf(l0-mm), w3 = __expf(l3-mm);
    float o0 = (w0*v0 + w3*v3) / (w0+w3);
    float q0 = leaky(p03), q3 = leaky(p33);
    float mq = fmaxf(q0, q3);
    float u0 = __expf(q0-mq), u3 = __expf(q3-mq);
    float o3 = (u0*v0 + u3*v3) / (u0+u3);
    out[i0] = o0; out[i3] = o3;
}

__global__ void k_relout(const float* __restrict__ rel_emb, const float* __restrict__ prop_W,
                         const float* __restrict__ prop_b, float* __restrict__ out){
    int r = blockIdx.x; int o = threadIdx.x;
    float acc = prop_b[r*256 + o];
    for (int i = 0; i < 64; i++) acc += rel_emb[r*64+i] * prop_W[(r*64+i)*256 + o];
    out[(size_t)4*NN*256 + r*256 + o] = acc;
}

extern "C" void kernel_launch(void* const* d_in, const int* in_sizes, int n_in,
                              void* d_out, int out_size, void* d_ws, size_t ws_size,
                              hipStream_t stream){
    const float* feat      = (const float*)d_in[0];
    const float* rel_emb   = (const float*)d_in[1];
    const float* node_W    = (const float*)d_in[2];
    const float* rel_W     = (const float*)d_in[3];
    const float* res_W     = (const float*)d_in[4];
    const float* res_b     = (const float*)d_in[5];
    const float* res_alpha = (const float*)d_in[6];
    const float* cross_attn= (const float*)d_in[7];
    const float* prop_W    = (const float*)d_in[8];
    const float* prop_b    = (const float*)d_in[9];
    const int* src_idx     = (const int*)d_in[10];
    const int* dst_idx     = (const int*)d_in[11];
    float* out = (float*)d_out;

    char* ws = (char*)d_ws;
    u32*   cnt     = (u32*)  (ws);                 //    800,000 B (4,NN)
    u32*   cnt2    = (u32*)  (ws + 800000);        //    800,000 B (4,NN)
    u32*   bsum    = (u32*)  (ws + 1600000);       //      4,096 B (4,256)
    u32*   row_ptr = (u32*)  (ws + 1604096);       //    800,016 B (4,NN+1)
    float* ra      = (float*)(ws + 2404112);       //      8,192 B (4,512)
    u16*   WcatS   = (u16*)  (ws + 2412304);       //  1,179,648 B (4,9,32,64,8) bf16
    float* e_comb  = (float*)(ws + 3591952);       // 12,800,000 B (4,NN,16) [src|dst]
    u32*   src_pack= (u32*)  (ws + 16391952);      //  3,200,000 B (4,NE)
    float* e_pack  = (float*)(ws + 19591952);      // 25,600,000 B (4,NE,8)
    u16*   fsrc    = (u16*)  (ws + 45191952);      //102,400,000 B (4,NN,256) bf16
    u16*   resb    = (u16*)  (ws + 147591952);     //102,400,000 B (4,NN,256) bf16
    // total: 249,991,952 B

    hipMemsetAsync(cnt, 0, 1604096, stream);  // cnt + cnt2 + bsum

    k_ra<<<4, 256, 0, stream>>>(rel_emb, rel_W, ra);
    k_wcat<<<(4*WCT*256)/256, 256, 0, stream>>>(node_W, res_W, ra, WcatS);
    dim3 gg((NN+63)/64, 4);
    k_gemm<<<gg, 256, 0, stream>>>(feat, WcatS, res_b, fsrc, resb, e_comb);

    dim3 geg((NE+255)/256, 4);
    k_count<<<geg, 256, 0, stream>>>(dst_idx, cnt);
    dim3 gsc((NN+255)/256, 4);
    k_scan1<<<gsc, 256, 0, stream>>>(cnt, bsum);
    k_scan2<<<4, 256, 0, stream>>>(bsum);
    k_scan3<<<gsc, 256, 0, stream>>>(cnt, bsum, row_ptr);
    k_scatter<<<geg, 256, 0, stream>>>(src_idx, dst_idx, e_comb, row_ptr, cnt2,
                                       src_pack, e_pack);
    dim3 ga((NN+3)/4, 4);
    k_agg<<<ga, 256, 0, stream>>>(row_ptr, src_pack, e_pack, fsrc, resb, res_alpha, out);

    k_cross<<<NN, 256, 0, stream>>>(out, cross_attn);
    k_relout<<<4, 256, 0, stream>>>(rel_emb, prop_W, prop_b, out);
}

// Round 8
// 464.563 us; speedup vs baseline: 1.7314x; 1.1871x over previous
//
#include <hip/hip_runtime.h>
#include <hip/hip_bf16.h>
#include <stdint.h>

typedef unsigned int u32;
typedef unsigned short u16;
typedef short short8 __attribute__((ext_vector_type(8)));
typedef float f32x4 __attribute__((ext_vector_type(4)));
typedef __attribute__((address_space(1))) const u32 gu32;
typedef __attribute__((address_space(3))) u32 lu32;

#define NN 50000
#define NE 200000
#define WCT 576     // 256 fsrc | 256 res | 8 e_src | 8 e_dst | 48 pad (cols of C)

__device__ __forceinline__ float leaky(float x){ return x >= 0.f ? x : 0.2f*x; }
__device__ __forceinline__ float bf2f(u16 u){ return __uint_as_float(((u32)u)<<16); }
__device__ __forceinline__ u16 f2bf(float f){            // RNE
    u32 u = __float_as_uint(f);
    u32 r = (u + 0x7fffu + ((u>>16)&1u)) >> 16;
    return (u16)r;
}
// pack 2 floats -> 2 bf16 (truncation) in ONE v_perm_b32
__device__ __forceinline__ u32 pack_bf2(float a, float b){
    return __builtin_amdgcn_perm(__float_as_uint(b), __float_as_uint(a), 0x07060302u);
}
__device__ __forceinline__ int nt_src(int r){ return (r==0)?0:((r==3)?2:1); }
__device__ __forceinline__ int nt_dst(int r){ return (r==1)?0:((r==2)?2:1); }

// ra[r][512] = rel_emb[r] @ rel_W[r]
__global__ void k_ra(const float* __restrict__ rel_emb, const float* __restrict__ rel_W,
                     float* __restrict__ ra){
    int r = blockIdx.x;
    for (int j = threadIdx.x; j < 512; j += blockDim.x){
        float acc = 0.f;
        for (int i = 0; i < 64; i++) acc += rel_emb[r*64+i] * rel_W[(r*64+i)*512 + j];
        ra[r*512 + j] = acc;
    }
}

// Assemble WcatS: chunk-transposed bf16 layout matching linear global_load_lds staging:
//   WcatS[((r*9+tile)*32 + kc)*512 + nrow*8 + off] = W^T[n=tile*64+nrow][k=kc*8+off]
__global__ void k_wcat(const float* __restrict__ node_W, const float* __restrict__ res_W,
                       const float* __restrict__ ra, u16* __restrict__ WcatS){
    int g = blockIdx.x*blockDim.x + threadIdx.x;
    if (g >= 4*WCT*256) return;
    int r = g/147456; int rem = g%147456;
    int tile = rem/16384; int rem2 = rem%16384;
    int kc = rem2/512; int rem3 = rem2%512;
    int nrow = rem3>>3; int off = rem3&7;
    int n = tile*64 + nrow;
    int k = kc*8 + off;
    int s = nt_src(r), d = nt_dst(r);
    float v;
    if (n < 256) v = node_W[(s*256+k)*256 + n];
    else if (n < 512) v = res_W[(d*256+k)*256 + (n-256)];
    else if (n < 520){ // e_src weights: node_W[s]·ra[h, D:]
        int h = n-512; float a = 0.f;
        for (int dd = 0; dd < 32; dd++) a += node_W[(s*256+k)*256 + h*32+dd] * ra[r*512 + h*64+32+dd];
        v = a;
    } else if (n < 528){ // e_dst weights: node_W[d]·ra[h, :D]
        int h = n-520; float a = 0.f;
        for (int dd = 0; dd < 32; dd++) a += node_W[(d*256+k)*256 + h*32+dd] * ra[r*512 + h*64+dd];
        v = a;
    } else v = 0.f;
    WcatS[g] = f2bf(v);
}

// MFMA GEMM, fat blocks: one block = 64-row strip x ALL 576 N.
// A K-resident in registers; B async-staged via global_load_lds, double-buffered.
__launch_bounds__(256)
__global__ void k_gemm(const float* __restrict__ feat, const u16* __restrict__ WcatS,
                       const float* __restrict__ res_b,
                       u16* __restrict__ fsrc, u16* __restrict__ resb,
                       float* __restrict__ e_comb){
    __shared__ uint4 lsB[4096];          // 2 x 32KB B double buffer
    __shared__ u16  cst[64*72];          // 9.2 KB epilogue C-stage, stride 72
    const short8* lsB8 = (const short8*)lsB;

    int r = blockIdx.y;
    int row0 = blockIdx.x*64;
    const float* A = feat + (size_t)r*NN*256;
    const u16*   W = WcatS + (size_t)r*9*16384;

    int t = threadIdx.x;
    int w = t>>6, l = t&63;
    int wm = (w>>1)*32, wn = (w&1)*32;
    int li = l & 15, lg = l >> 4;

    // ---- A fragments: direct global -> registers, K-resident (64 VGPR/lane)
    short8 afr[2][8];
    #pragma unroll
    for (int mt = 0; mt < 2; mt++){
        int grow = row0 + wm + mt*16 + li; if (grow > NN-1) grow = NN-1;
        const float* ap = A + (size_t)grow*256 + lg*8;
        #pragma unroll
        for (int kk = 0; kk < 8; kk++){
            float4 x = *(const float4*)(ap + kk*32);
            float4 y = *(const float4*)(ap + kk*32 + 4);
            short8 f;
            ((u32*)&f)[0] = pack_bf2(x.x, x.y);
            ((u32*)&f)[1] = pack_bf2(x.z, x.w);
            ((u32*)&f)[2] = pack_bf2(y.x, y.y);
            ((u32*)&f)[3] = pack_bf2(y.z, y.w);
            afr[mt][kk] = f;
        }
    }

    // ---- prologue: stage tile 0 into buf 0 (async direct-to-LDS)
    #pragma unroll
    for (int i = 0; i < 8; i++){
        int chunk = w*512 + i*64 + l;
        __builtin_amdgcn_global_load_lds((gu32*)(W + (size_t)chunk*8),
                                         (lu32*)((char*)lsB + (w*512 + i*64)*16), 16, 0, 0);
    }
    __syncthreads();

    int d = nt_dst(r);
    int orow = t>>2, oq = t&3;
    int ogrow = row0 + orow;
    size_t onidx = (size_t)r*NN + ogrow;

    for (int T = 0; T < 8; T++){
        int cur = T & 1;
        // issue async stage of tile T+1 into the other buffer (flies under MFMA)
        {
            const u16* tb = W + (size_t)(T+1)*16384;
            char* lb = (char*)lsB + (cur^1)*32768;
            #pragma unroll
            for (int i = 0; i < 8; i++){
                int chunk = w*512 + i*64 + l;
                __builtin_amdgcn_global_load_lds((gu32*)(tb + (size_t)chunk*8),
                                                 (lu32*)(lb + (w*512 + i*64)*16), 16, 0, 0);
            }
        }
        // compute tile T from buf[cur]
        f32x4 acc[2][2] = {};
        #pragma unroll
        for (int kk = 0; kk < 8; kk++){
            short8 bfr[2];
            #pragma unroll
            for (int nt = 0; nt < 2; nt++)
                bfr[nt] = lsB8[cur*2048 + (kk*4+lg)*64 + wn + nt*16 + li];
            #pragma unroll
            for (int mt = 0; mt < 2; mt++)
                #pragma unroll
                for (int nt = 0; nt < 2; nt++)
                    acc[mt][nt] = __builtin_amdgcn_mfma_f32_16x16x32_bf16(afr[mt][kk], bfr[nt], acc[mt][nt], 0,0,0);
        }
        // epilogue: stage to LDS (bf16), then line-complete dwordx4 stores
        float bias[2] = {0.f, 0.f};
        if (T >= 4){
            bias[0] = res_b[d*256 + (T-4)*64 + wn + li];
            bias[1] = res_b[d*256 + (T-4)*64 + wn + 16 + li];
        }
        #pragma unroll
        for (int mt = 0; mt < 2; mt++)
            #pragma unroll
            for (int nt = 0; nt < 2; nt++)
                #pragma unroll
                for (int qq = 0; qq < 4; qq++)
                    cst[(wm + mt*16 + lg*4 + qq)*72 + wn + nt*16 + li] = f2bf(acc[mt][nt][qq] + bias[nt]);
        __syncthreads();   // cst visible; drains async loads (tile T+1 ready)
        if (ogrow < NN){
            u16* dst = (T < 4) ? (fsrc + onidx*256 + T*64) : (resb + onidx*256 + (T-4)*64);
            const uint4* src = (const uint4*)(cst + orow*72 + oq*16);
            uint4* dq = (uint4*)(dst + oq*16);
            dq[0] = src[0];
            dq[1] = src[1];
        }
        __syncthreads();   // cst reads done before next iteration overwrites
    }

    // ---- tile 8: e-columns 512..527 (nrow 0..15 of tile 8, in buf 0) -> e_comb
    if (wn == 0){
        f32x4 acc[2] = {};
        #pragma unroll
        for (int kk = 0; kk < 8; kk++){
            short8 bfr = lsB8[(kk*4+lg)*64 + li];
            #pragma unroll
            for (int mt = 0; mt < 2; mt++)
                acc[mt] = __builtin_amdgcn_mfma_f32_16x16x32_bf16(afr[mt][kk], bfr, acc[mt], 0,0,0);
        }
        #pragma unroll
        for (int mt = 0; mt < 2; mt++)
            #pragma unroll
            for (int qq = 0; qq < 4; qq++){
                int row = row0 + wm + mt*16 + lg*4 + qq;
                if (row < NN)
                    e_comb[((size_t)r*NN + row)*16 + li] = acc[mt][qq];
            }
    }
}

// ---- CSR build: count -> hierarchical scan -> scatter ----

__global__ void k_count(const int* __restrict__ dst_idx, u32* __restrict__ cnt){
    int r = blockIdx.y; int e = blockIdx.x*256 + threadIdx.x;
    if (e >= NE) return;
    atomicAdd(&cnt[r*NN + dst_idx[r*NE+e]], 1u);
}

__global__ void k_scan1(const u32* __restrict__ cnt, u32* __restrict__ bsum){
    int r = blockIdx.y, b = blockIdx.x;
    int i = b*256 + threadIdx.x;
    u32 v = (i < NN) ? cnt[r*NN+i] : 0u;
    #pragma unroll
    for (int off = 1; off < 64; off <<= 1) v += __shfl_xor(v, off, 64);
    __shared__ u32 wsum[4];
    int lane = threadIdx.x & 63, w = threadIdx.x >> 6;
    if (lane == 0) wsum[w] = v;
    __syncthreads();
    if (threadIdx.x == 0) bsum[r*256 + b] = wsum[0]+wsum[1]+wsum[2]+wsum[3];
}

__device__ __forceinline__ u32 block_scan_incl(u32 v){
    __shared__ u32 wsum[4];
    int lane = threadIdx.x & 63, w = threadIdx.x >> 6;
    #pragma unroll
    for (int off = 1; off < 64; off <<= 1){
        u32 t = __shfl_up(v, off, 64);
        if (lane >= off) v += t;
    }
    if (lane == 63) wsum[w] = v;
    __syncthreads();
    u32 add = 0;
    #pragma unroll
    for (int k = 0; k < 4; k++) if (k < w) add += wsum[k];
    return v + add;
}

__global__ void k_scan2(u32* __restrict__ bsum){
    int r = blockIdx.x;
    u32 v = bsum[r*256 + threadIdx.x];
    u32 incl = block_scan_incl(v);
    bsum[r*256 + threadIdx.x] = incl - v;
}

__global__ void k_scan3(const u32* __restrict__ cnt, const u32* __restrict__ bsum,
                        u32* __restrict__ row_ptr){
    int r = blockIdx.y, b = blockIdx.x;
    int i = b*256 + threadIdx.x;
    u32 v = (i < NN) ? cnt[r*NN+i] : 0u;
    u32 incl = block_scan_incl(v);
    if (i < NN) row_ptr[r*(NN+1) + i + 1] = bsum[r*256 + b] + incl;
    if (b == 0 && threadIdx.x == 0) row_ptr[r*(NN+1)] = 0u;
}

__global__ void k_scatter(const int* __restrict__ src_idx, const int* __restrict__ dst_idx,
                          const float* __restrict__ e_comb,
                          const u32* __restrict__ row_ptr, u32* __restrict__ cnt2,
                          u32* __restrict__ src_pack, float* __restrict__ e_pack){
    int r = blockIdx.y; int e = blockIdx.x*256 + threadIdx.x;
    if (e >= NE) return;
    int s = src_idx[r*NE+e], d = dst_idx[r*NE+e];
    u32 pos = row_ptr[r*(NN+1)+d] + atomicAdd(&cnt2[r*NN+d], 1u);
    src_pack[r*NE + pos] = (u32)s;
    const float* es = e_comb + (size_t)(r*NN+s)*16;
    const float* ed = e_comb + (size_t)(r*NN+d)*16 + 8;
    float* ep = e_pack + ((size_t)(r*NE)+pos)*8;
    #pragma unroll
    for (int h = 0; h < 8; h++) ep[h] = leaky(es[h] + ed[h]);
}

// Fused aggregation + residual gate + cross-attention. One block per node;
// wave w = relation w. Relations 0,3 exchange conv rows + per-head dots via
// LDS, apply cross softmax, and every out row is written exactly once.
__launch_bounds__(256)
__global__ void k_aggx(const u32* __restrict__ row_ptr, const u32* __restrict__ src_pack,
                       const float* __restrict__ e_pack, const u16* __restrict__ fsrc,
                       const u16* __restrict__ resb, const float* __restrict__ res_alpha,
                       const float* __restrict__ cross_attn, float* __restrict__ out){
    __shared__ float cbuf[2][256];   // conv rows of relations 0 and 3
    __shared__ float dots[4][8];     // [c0·ca0, c0·ca3, c3·ca0, c3·ca3][head]

    int n = blockIdx.x;
    int r = threadIdx.x >> 6;        // relation = wave id
    int l = threadIdx.x & 63;
    int h = l >> 3;

    u32 p0 = row_ptr[r*(NN+1)+n];
    u32 p1 = row_ptr[r*(NN+1)+n+1];
    int deg = (int)(p1 - p0);

    // phase 1: online (max, sumexp); lane l covers edge stripe (l>>3), head (l&7)
    float m = -1e30f, s = 0.f;
    for (int i = (l>>3); i < deg; i += 8){
        float e = e_pack[((size_t)(r*NE) + p0 + i)*8 + (l&7)];
        float mn = fmaxf(m, e);
        s = s*__expf(m - mn) + __expf(e - mn);
        m = mn;
    }
    #pragma unroll
    for (int msk = 8; msk < 64; msk <<= 1){
        float m2 = __shfl_xor(m, msk, 64);
        float s2 = __shfl_xor(s, msk, 64);
        float mn = fmaxf(m, m2);
        s = s*__expf(m - mn) + s2*__expf(m2 - mn);
        m = mn;
    }
    float mh = __shfl(m, h, 64);
    float sh = __shfl(s, h, 64);
    float inv_sh = 1.0f / sh;

    // phase 2: gather-accumulate; src indices preloaded + shfl-broadcast,
    // 2-way unrolled so two 512B gathers fly concurrently.
    float a0=0.f, a1=0.f, a2=0.f, a3=0.f;
    const size_t ebase = (size_t)r*NE + p0;
    const u16* fbase = fsrc + (size_t)r*NN*256;
    for (int base = 0; base < deg; base += 64){
        int rem = deg - base; if (rem > 64) rem = 64;
        u32 my_src = 0;
        if (l < rem) my_src = src_pack[ebase + base + l];
        int i = 0;
        for (; i+2 <= rem; i += 2){
            u32 s0 = __shfl(my_src, i, 64);
            u32 s1 = __shfl(my_src, i+1, 64);
            float e0 = e_pack[(ebase + base + i)*8 + h];
            float e1 = e_pack[(ebase + base + i + 1)*8 + h];
            ushort4 f0 = *(const ushort4*)(fbase + (size_t)s0*256 + l*4);
            ushort4 f1 = *(const ushort4*)(fbase + (size_t)s1*256 + l*4);
            float w0 = __expf(e0 - mh)*inv_sh;
            float w1 = __expf(e1 - mh)*inv_sh;
            a0 += bf2f(f0.x)*w0 + bf2f(f1.x)*w1;
            a1 += bf2f(f0.y)*w0 + bf2f(f1.y)*w1;
            a2 += bf2f(f0.z)*w0 + bf2f(f1.z)*w1;
            a3 += bf2f(f0.w)*w0 + bf2f(f1.w)*w1;
        }
        if (i < rem){
            u32 s0 = __shfl(my_src, i, 64);
            float e0 = e_pack[(ebase + base + i)*8 + h];
            ushort4 f0 = *(const ushort4*)(fbase + (size_t)s0*256 + l*4);
            float w0 = __expf(e0 - mh)*inv_sh;
            a0 += bf2f(f0.x)*w0; a1 += bf2f(f0.y)*w0; a2 += bf2f(f0.z)*w0; a3 += bf2f(f0.w)*w0;
        }
    }

    // residual gate
    int d = nt_dst(r);
    float alpha = 1.f/(1.f + __expf(-res_alpha[d]));
    float beta = 1.f - alpha;
    ushort4 rv = *(const ushort4*)(resb + ((size_t)r*NN+n)*256 + l*4);
    float c0 = fmaxf(a0,0.f)*alpha + bf2f(rv.x)*beta;
    float c1 = fmaxf(a1,0.f)*alpha + bf2f(rv.y)*beta;
    float c2 = fmaxf(a2,0.f)*alpha + bf2f(rv.z)*beta;
    float c3 = fmaxf(a3,0.f)*alpha + bf2f(rv.w)*beta;

    if (r == 1 || r == 2){
        float4 o = {c0, c1, c2, c3};
        *(float4*)(out + ((size_t)r*NN+n)*256 + l*4) = o;
    } else {
        int slot = (r == 0) ? 0 : 1;
        cbuf[slot][l*4+0] = c0; cbuf[slot][l*4+1] = c1;
        cbuf[slot][l*4+2] = c2; cbuf[slot][l*4+3] = c3;
        const float* ca0 = cross_attn;            // relation 0 weights
        const float* ca3 = cross_attn + 3*256;    // relation 3 weights
        float d0 = c0*ca0[l*4+0] + c1*ca0[l*4+1] + c2*ca0[l*4+2] + c3*ca0[l*4+3];
        float d3 = c0*ca3[l*4+0] + c1*ca3[l*4+1] + c2*ca3[l*4+2] + c3*ca3[l*4+3];
        #pragma unroll
        for (int msk = 1; msk < 8; msk <<= 1){
            d0 += __shfl_xor(d0, msk, 64);
            d3 += __shfl_xor(d3, msk, 64);
        }
        if ((l & 7) == 0){
            dots[slot*2+0][h] = d0;
            dots[slot*2+1][h] = d3;
        }
    }
    __syncthreads();
    if (r == 0 || r == 3){
        // out r uses cross_attn[r]: logits = (conv0·ca_r, conv3·ca_r) per head
        float g0 = (r == 0) ? dots[0][h] : dots[1][h];
        float g3 = (r == 0) ? dots[2][h] : dots[3][h];
        g0 = leaky(g0); g3 = leaky(g3);
        float mm = fmaxf(g0, g3);
        float w0 = __expf(g0-mm), w3 = __expf(g3-mm);
        float inv = 1.f/(w0+w3);
        w0 *= inv; w3 *= inv;
        float4 o;
        o.x = w0*cbuf[0][l*4+0] + w3*cbuf[1][l*4+0];
        o.y = w0*cbuf[0][l*4+1] + w3*cbuf[1][l*4+1];
        o.z = w0*cbuf[0][l*4+2] + w3*cbuf[1][l*4+2];
        o.w = w0*cbuf[0][l*4+3] + w3*cbuf[1][l*4+3];
        *(float4*)(out + ((size_t)r*NN+n)*256 + l*4) = o;
    }
}

__global__ void k_relout(const float* __restrict__ rel_emb, const float* __restrict__ prop_W,
                         const float* __restrict__ prop_b, float* __restrict__ out){
    int r = blockIdx.x; int o = threadIdx.x;
    float acc = prop_b[r*256 + o];
    for (int i = 0; i < 64; i++) acc += rel_emb[r*64+i] * prop_W[(r*64+i)*256 + o];
    out[(size_t)4*NN*256 + r*256 + o] = acc;
}

extern "C" void kernel_launch(void* const* d_in, const int* in_sizes, int n_in,
                              void* d_out, int out_size, void* d_ws, size_t ws_size,
                              hipStream_t stream){
    const float* feat      = (const float*)d_in[0];
    const float* rel_emb   = (const float*)d_in[1];
    const float* node_W    = (const float*)d_in[2];
    const float* rel_W     = (const float*)d_in[3];
    const float* res_W     = (const float*)d_in[4];
    const float* res_b     = (const float*)d_in[5];
    const float* res_alpha = (const float*)d_in[6];
    const float* cross_attn= (const float*)d_in[7];
    const float* prop_W    = (const float*)d_in[8];
    const float* prop_b    = (const float*)d_in[9];
    const int* src_idx     = (const int*)d_in[10];
    const int* dst_idx     = (const int*)d_in[11];
    float* out = (float*)d_out;

    char* ws = (char*)d_ws;
    u32*   cnt     = (u32*)  (ws);                 //    800,000 B (4,NN)
    u32*   cnt2    = (u32*)  (ws + 800000);        //    800,000 B (4,NN)
    u32*   bsum    = (u32*)  (ws + 1600000);       //      4,096 B (4,256)
    u32*   row_ptr = (u32*)  (ws + 1604096);       //    800,016 B (4,NN+1)
    float* ra      = (float*)(ws + 2404112);       //      8,192 B (4,512)
    u16*   WcatS   = (u16*)  (ws + 2412304);       //  1,179,648 B (4,9,32,64,8) bf16
    float* e_comb  = (float*)(ws + 3591952);       // 12,800,000 B (4,NN,16) [src|dst]
    u32*   src_pack= (u32*)  (ws + 16391952);      //  3,200,000 B (4,NE)
    float* e_pack  = (float*)(ws + 19591952);      // 25,600,000 B (4,NE,8)
    u16*   fsrc    = (u16*)  (ws + 45191952);      //102,400,000 B (4,NN,256) bf16
    u16*   resb    = (u16*)  (ws + 147591952);     //102,400,000 B (4,NN,256) bf16
    // total: 249,991,952 B

    hipMemsetAsync(cnt, 0, 1604096, stream);  // cnt + cnt2 + bsum

    k_ra<<<4, 256, 0, stream>>>(rel_emb, rel_W, ra);
    k_wcat<<<(4*WCT*256)/256, 256, 0, stream>>>(node_W, res_W, ra, WcatS);
    dim3 gg((NN+63)/64, 4);
    k_gemm<<<gg, 256, 0, stream>>>(feat, WcatS, res_b, fsrc, resb, e_comb);

    dim3 geg((NE+255)/256, 4);
    k_count<<<geg, 256, 0, stream>>>(dst_idx, cnt);
    dim3 gsc((NN+255)/256, 4);
    k_scan1<<<gsc, 256, 0, stream>>>(cnt, bsum);
    k_scan2<<<4, 256, 0, stream>>>(bsum);
    k_scan3<<<gsc, 256, 0, stream>>>(cnt, bsum, row_ptr);
    k_scatter<<<geg, 256, 0, stream>>>(src_idx, dst_idx, e_comb, row_ptr, cnt2,
                                       src_pack, e_pack);
    k_aggx<<<NN, 256, 0, stream>>>(row_ptr, src_pack, e_pack, fsrc, resb,
                                   res_alpha, cross_attn, out);
    k_relout<<<4, 256, 0, stream>>>(rel_emb, prop_W, prop_b, out);
}

// Round 10
// 446.327 us; speedup vs baseline: 1.8021x; 1.0409x over previous
//
#include <hip/hip_runtime.h>
#include <hip/hip_bf16.h>
#include <stdint.h>

typedef unsigned int u32;
typedef unsigned short u16;
typedef short short8 __attribute__((ext_vector_type(8)));
typedef float f32x4 __attribute__((ext_vector_type(4)));
typedef unsigned short u16x4 __attribute__((ext_vector_type(4)));
typedef __attribute__((address_space(1))) const u32 gu32;
typedef __attribute__((address_space(3))) u32 lu32;

#define NN 50000
#define NE 200000
#define WCT 576     // 256 fsrc | 256 res | 8 e_src | 8 e_dst | 48 pad (cols of C)

__device__ __forceinline__ float leaky(float x){ return x >= 0.f ? x : 0.2f*x; }
__device__ __forceinline__ float bf2f(u16 u){ return __uint_as_float(((u32)u)<<16); }
__device__ __forceinline__ u16 f2bf(float f){            // RNE
    u32 u = __float_as_uint(f);
    u32 r = (u + 0x7fffu + ((u>>16)&1u)) >> 16;
    return (u16)r;
}
// pack 2 floats -> 2 bf16 (truncation) in ONE v_perm_b32
__device__ __forceinline__ u32 pack_bf2(float a, float b){
    return __builtin_amdgcn_perm(__float_as_uint(b), __float_as_uint(a), 0x07060302u);
}
__device__ __forceinline__ int nt_src(int r){ return (r==0)?0:((r==3)?2:1); }
__device__ __forceinline__ int nt_dst(int r){ return (r==1)?0:((r==2)?2:1); }

// ra[r][512] = rel_emb[r] @ rel_W[r]
__global__ void k_ra(const float* __restrict__ rel_emb, const float* __restrict__ rel_W,
                     float* __restrict__ ra){
    int r = blockIdx.x;
    for (int j = threadIdx.x; j < 512; j += blockDim.x){
        float acc = 0.f;
        for (int i = 0; i < 64; i++) acc += rel_emb[r*64+i] * rel_W[(r*64+i)*512 + j];
        ra[r*512 + j] = acc;
    }
}

// Assemble WcatS: chunk-transposed bf16 layout matching linear global_load_lds staging:
//   WcatS[((r*9+tile)*32 + kc)*512 + nrow*8 + off] = W^T[n=tile*64+nrow][k=kc*8+off]
__global__ void k_wcat(const float* __restrict__ node_W, const float* __restrict__ res_W,
                       const float* __restrict__ ra, u16* __restrict__ WcatS){
    int g = blockIdx.x*blockDim.x + threadIdx.x;
    if (g >= 4*WCT*256) return;
    int r = g/147456; int rem = g%147456;
    int tile = rem/16384; int rem2 = rem%16384;
    int kc = rem2/512; int rem3 = rem2%512;
    int nrow = rem3>>3; int off = rem3&7;
    int n = tile*64 + nrow;
    int k = kc*8 + off;
    int s = nt_src(r), d = nt_dst(r);
    float v;
    if (n < 256) v = node_W[(s*256+k)*256 + n];
    else if (n < 512) v = res_W[(d*256+k)*256 + (n-256)];
    else if (n < 520){ // e_src weights: node_W[s]·ra[h, D:]
        int h = n-512; float a = 0.f;
        for (int dd = 0; dd < 32; dd++) a += node_W[(s*256+k)*256 + h*32+dd] * ra[r*512 + h*64+32+dd];
        v = a;
    } else if (n < 528){ // e_dst weights: node_W[d]·ra[h, :D]
        int h = n-520; float a = 0.f;
        for (int dd = 0; dd < 32; dd++) a += node_W[(d*256+k)*256 + h*32+dd] * ra[r*512 + h*64+dd];
        v = a;
    } else v = 0.f;
    WcatS[g] = f2bf(v);
}

// MFMA GEMM, fat blocks: one block = 64-row strip x ALL 576 N.
// A K-resident in registers; B async-staged via global_load_lds, double-buffered.
__launch_bounds__(256)
__global__ void k_gemm(const float* __restrict__ feat, const u16* __restrict__ WcatS,
                       const float* __restrict__ res_b,
                       u16* __restrict__ fsrc, u16* __restrict__ resb,
                       float* __restrict__ e_comb){
    __shared__ uint4 lsB[4096];          // 2 x 32KB B double buffer
    __shared__ u16  cst[64*72];          // 9.2 KB epilogue C-stage, stride 72
    const short8* lsB8 = (const short8*)lsB;

    int r = blockIdx.y;
    int row0 = blockIdx.x*64;
    const float* A = feat + (size_t)r*NN*256;
    const u16*   W = WcatS + (size_t)r*9*16384;

    int t = threadIdx.x;
    int w = t>>6, l = t&63;
    int wm = (w>>1)*32, wn = (w&1)*32;
    int li = l & 15, lg = l >> 4;

    // ---- A fragments: direct global -> registers, K-resident (64 VGPR/lane)
    short8 afr[2][8];
    #pragma unroll
    for (int mt = 0; mt < 2; mt++){
        int grow = row0 + wm + mt*16 + li; if (grow > NN-1) grow = NN-1;
        const float* ap = A + (size_t)grow*256 + lg*8;
        #pragma unroll
        for (int kk = 0; kk < 8; kk++){
            f32x4 x = __builtin_nontemporal_load((const f32x4*)(ap + kk*32));
            f32x4 y = __builtin_nontemporal_load((const f32x4*)(ap + kk*32 + 4));
            short8 f;
            ((u32*)&f)[0] = pack_bf2(x.x, x.y);
            ((u32*)&f)[1] = pack_bf2(x.z, x.w);
            ((u32*)&f)[2] = pack_bf2(y.x, y.y);
            ((u32*)&f)[3] = pack_bf2(y.z, y.w);
            afr[mt][kk] = f;
        }
    }

    // ---- prologue: stage tile 0 into buf 0 (async direct-to-LDS)
    #pragma unroll
    for (int i = 0; i < 8; i++){
        int chunk = w*512 + i*64 + l;
        __builtin_amdgcn_global_load_lds((gu32*)(W + (size_t)chunk*8),
                                         (lu32*)((char*)lsB + (w*512 + i*64)*16), 16, 0, 0);
    }
    __syncthreads();

    int d = nt_dst(r);
    int orow = t>>2, oq = t&3;
    int ogrow = row0 + orow;
    size_t onidx = (size_t)r*NN + ogrow;

    for (int T = 0; T < 8; T++){
        int cur = T & 1;
        // issue async stage of tile T+1 into the other buffer (flies under MFMA)
        {
            const u16* tb = W + (size_t)(T+1)*16384;
            char* lb = (char*)lsB + (cur^1)*32768;
            #pragma unroll
            for (int i = 0; i < 8; i++){
                int chunk = w*512 + i*64 + l;
                __builtin_amdgcn_global_load_lds((gu32*)(tb + (size_t)chunk*8),
                                                 (lu32*)(lb + (w*512 + i*64)*16), 16, 0, 0);
            }
        }
        // compute tile T from buf[cur]
        f32x4 acc[2][2] = {};
        #pragma unroll
        for (int kk = 0; kk < 8; kk++){
            short8 bfr[2];
            #pragma unroll
            for (int nt = 0; nt < 2; nt++)
                bfr[nt] = lsB8[cur*2048 + (kk*4+lg)*64 + wn + nt*16 + li];
            #pragma unroll
            for (int mt = 0; mt < 2; mt++)
                #pragma unroll
                for (int nt = 0; nt < 2; nt++)
                    acc[mt][nt] = __builtin_amdgcn_mfma_f32_16x16x32_bf16(afr[mt][kk], bfr[nt], acc[mt][nt], 0,0,0);
        }
        // epilogue: stage to LDS (bf16), then line-complete dwordx4 stores
        float bias[2] = {0.f, 0.f};
        if (T >= 4){
            bias[0] = res_b[d*256 + (T-4)*64 + wn + li];
            bias[1] = res_b[d*256 + (T-4)*64 + wn + 16 + li];
        }
        #pragma unroll
        for (int mt = 0; mt < 2; mt++)
            #pragma unroll
            for (int nt = 0; nt < 2; nt++)
                #pragma unroll
                for (int qq = 0; qq < 4; qq++)
                    cst[(wm + mt*16 + lg*4 + qq)*72 + wn + nt*16 + li] = f2bf(acc[mt][nt][qq] + bias[nt]);
        __syncthreads();   // cst visible; drains async loads (tile T+1 ready)
        if (ogrow < NN){
            u16* dst = (T < 4) ? (fsrc + onidx*256 + T*64) : (resb + onidx*256 + (T-4)*64);
            const uint4* src = (const uint4*)(cst + orow*72 + oq*16);
            uint4* dq = (uint4*)(dst + oq*16);
            dq[0] = src[0];
            dq[1] = src[1];
        }
        __syncthreads();   // cst reads done before next iteration overwrites
    }

    // ---- tile 8: e-columns 512..527 (nrow 0..15 of tile 8, in buf 0) -> e_comb
    if (wn == 0){
        f32x4 acc[2] = {};
        #pragma unroll
        for (int kk = 0; kk < 8; kk++){
            short8 bfr = lsB8[(kk*4+lg)*64 + li];
            #pragma unroll
            for (int mt = 0; mt < 2; mt++)
                acc[mt] = __builtin_amdgcn_mfma_f32_16x16x32_bf16(afr[mt][kk], bfr, acc[mt], 0,0,0);
        }
        #pragma unroll
        for (int mt = 0; mt < 2; mt++)
            #pragma unroll
            for (int qq = 0; qq < 4; qq++){
                int row = row0 + wm + mt*16 + lg*4 + qq;
                if (row < NN)
                    e_comb[((size_t)r*NN + row)*16 + li] = acc[mt][qq];
            }
    }
}

// ---- CSR build: count -> hierarchical scan -> scatter ----

__global__ void k_count(const int* __restrict__ dst_idx, u32* __restrict__ cnt){
    int r = blockIdx.y; int e = blockIdx.x*256 + threadIdx.x;
    if (e >= NE) return;
    atomicAdd(&cnt[r*NN + dst_idx[r*NE+e]], 1u);
}

__global__ void k_scan1(const u32* __restrict__ cnt, u32* __restrict__ bsum){
    int r = blockIdx.y, b = blockIdx.x;
    int i = b*256 + threadIdx.x;
    u32 v = (i < NN) ? cnt[r*NN+i] : 0u;
    #pragma unroll
    for (int off = 1; off < 64; off <<= 1) v += __shfl_xor(v, off, 64);
    __shared__ u32 wsum[4];
    int lane = threadIdx.x & 63, w = threadIdx.x >> 6;
    if (lane == 0) wsum[w] = v;
    __syncthreads();
    if (threadIdx.x == 0) bsum[r*256 + b] = wsum[0]+wsum[1]+wsum[2]+wsum[3];
}

__device__ __forceinline__ u32 block_scan_incl(u32 v){
    __shared__ u32 wsum[4];
    int lane = threadIdx.x & 63, w = threadIdx.x >> 6;
    #pragma unroll
    for (int off = 1; off < 64; off <<= 1){
        u32 t = __shfl_up(v, off, 64);
        if (lane >= off) v += t;
    }
    if (lane == 63) wsum[w] = v;
    __syncthreads();
    u32 add = 0;
    #pragma unroll
    for (int k = 0; k < 4; k++) if (k < w) add += wsum[k];
    return v + add;
}

__global__ void k_scan2(u32* __restrict__ bsum){
    int r = blockIdx.x;
    u32 v = bsum[r*256 + threadIdx.x];
    u32 incl = block_scan_incl(v);
    bsum[r*256 + threadIdx.x] = incl - v;
}

__global__ void k_scan3(const u32* __restrict__ cnt, const u32* __restrict__ bsum,
                        u32* __restrict__ row_ptr){
    int r = blockIdx.y, b = blockIdx.x;
    int i = b*256 + threadIdx.x;
    u32 v = (i < NN) ? cnt[r*NN+i] : 0u;
    u32 incl = block_scan_incl(v);
    if (i < NN) row_ptr[r*(NN+1) + i + 1] = bsum[r*256 + b] + incl;
    if (b == 0 && threadIdx.x == 0) row_ptr[r*(NN+1)] = 0u;
}

// per edge: pos in dst bucket; payload = src + 8 PRE-EXPONENTIATED logits
// (exp without max-subtraction is safe: |logit| <~ 20 << 88 at this data scale)
__global__ void k_scatter(const int* __restrict__ src_idx, const int* __restrict__ dst_idx,
                          const float* __restrict__ e_comb,
                          const u32* __restrict__ row_ptr, u32* __restrict__ cnt2,
                          u32* __restrict__ src_pack, float* __restrict__ e_pack){
    int r = blockIdx.y; int e = blockIdx.x*256 + threadIdx.x;
    if (e >= NE) return;
    int s = src_idx[r*NE+e], d = dst_idx[r*NE+e];
    u32 pos = row_ptr[r*(NN+1)+d] + atomicAdd(&cnt2[r*NN+d], 1u);
    src_pack[r*NE + pos] = (u32)s;
    const f32x4* es = (const f32x4*)(e_comb + (size_t)(r*NN+s)*16);
    const f32x4* ed = (const f32x4*)(e_comb + (size_t)(r*NN+d)*16 + 8);
    f32x4 s0 = es[0], s1 = es[1], d0 = ed[0], d1 = ed[1];
    f32x4 w0, w1;
    w0.x = __expf(leaky(s0.x+d0.x)); w0.y = __expf(leaky(s0.y+d0.y));
    w0.z = __expf(leaky(s0.z+d0.z)); w0.w = __expf(leaky(s0.w+d0.w));
    w1.x = __expf(leaky(s1.x+d1.x)); w1.y = __expf(leaky(s1.y+d1.y));
    w1.z = __expf(leaky(s1.z+d1.z)); w1.w = __expf(leaky(s1.w+d1.w));
    f32x4* ep = (f32x4*)(e_pack + ((size_t)(r*NE)+pos)*8);
    ep[0] = w0; ep[1] = w1;
}

// Fused aggregation + residual gate + cross-attention. One block per node;
// wave w = relation w. e_pack holds exp(logit): phase 1 = plain sum,
// phase 2 weight = ex * inv_sh (no exp in the hot loop). Streaming data
// (resb in, out) uses non-temporal ops to keep L3 for the fsrc gathers.
__launch_bounds__(256)
__global__ void k_aggx(const u32* __restrict__ row_ptr, const u32* __restrict__ src_pack,
                       const float* __restrict__ e_pack, const u16* __restrict__ fsrc,
                       const u16* __restrict__ resb, const float* __restrict__ res_alpha,
                       const float* __restrict__ cross_attn, float* __restrict__ out){
    __shared__ float cbuf[2][256];   // conv rows of relations 0 and 3
    __shared__ float dots[4][8];     // [c0·ca0, c0·ca3, c3·ca0, c3·ca3][head]

    int n = blockIdx.x;
    int r = threadIdx.x >> 6;        // relation = wave id
    int l = threadIdx.x & 63;
    int h = l >> 3;

    u32 p0 = row_ptr[r*(NN+1)+n];
    u32 p1 = row_ptr[r*(NN+1)+n+1];
    int deg = (int)(p1 - p0);

    // phase 1: plain sum of pre-exponentiated weights
    float s = 0.f;
    for (int i = (l>>3); i < deg; i += 8)
        s += e_pack[((size_t)(r*NE) + p0 + i)*8 + (l&7)];
    #pragma unroll
    for (int msk = 8; msk < 64; msk <<= 1)
        s += __shfl_xor(s, msk, 64);
    float sh = __shfl(s, h, 64);
    float inv_sh = (deg > 0) ? 1.0f / sh : 0.f;

    // phase 2: gather-accumulate; src preloaded + shfl-broadcast, 4-way unroll
    float a0=0.f, a1=0.f, a2=0.f, a3=0.f;
    const size_t ebase = (size_t)r*NE + p0;
    const u16* fbase = fsrc + (size_t)r*NN*256;
    for (int base = 0; base < deg; base += 64){
        int rem = deg - base; if (rem > 64) rem = 64;
        u32 my_src = 0;
        if (l < rem) my_src = src_pack[ebase + base + l];
        int i = 0;
        for (; i+4 <= rem; i += 4){
            u32 s0 = __shfl(my_src, i, 64);
            u32 s1 = __shfl(my_src, i+1, 64);
            u32 s2 = __shfl(my_src, i+2, 64);
            u32 s3 = __shfl(my_src, i+3, 64);
            float ex0 = e_pack[(ebase + base + i)*8 + h];
            float ex1 = e_pack[(ebase + base + i + 1)*8 + h];
            float ex2 = e_pack[(ebase + base + i + 2)*8 + h];
            float ex3 = e_pack[(ebase + base + i + 3)*8 + h];
            ushort4 f0 = *(const ushort4*)(fbase + (size_t)s0*256 + l*4);
            ushort4 f1 = *(const ushort4*)(fbase + (size_t)s1*256 + l*4);
            ushort4 f2 = *(const ushort4*)(fbase + (size_t)s2*256 + l*4);
            ushort4 f3 = *(const ushort4*)(fbase + (size_t)s3*256 + l*4);
            float w0 = ex0*inv_sh, w1 = ex1*inv_sh, w2 = ex2*inv_sh, w3 = ex3*inv_sh;
            a0 += bf2f(f0.x)*w0 + bf2f(f1.x)*w1 + bf2f(f2.x)*w2 + bf2f(f3.x)*w3;
            a1 += bf2f(f0.y)*w0 + bf2f(f1.y)*w1 + bf2f(f2.y)*w2 + bf2f(f3.y)*w3;
            a2 += bf2f(f0.z)*w0 + bf2f(f1.z)*w1 + bf2f(f2.z)*w2 + bf2f(f3.z)*w3;
            a3 += bf2f(f0.w)*w0 + bf2f(f1.w)*w1 + bf2f(f2.w)*w2 + bf2f(f3.w)*w3;
        }
        for (; i < rem; i++){
            u32 s0 = __shfl(my_src, i, 64);
            float w0 = e_pack[(ebase + base + i)*8 + h]*inv_sh;
            ushort4 f0 = *(const ushort4*)(fbase + (size_t)s0*256 + l*4);
            a0 += bf2f(f0.x)*w0; a1 += bf2f(f0.y)*w0; a2 += bf2f(f0.z)*w0; a3 += bf2f(f0.w)*w0;
        }
    }

    // residual gate (resb streamed non-temporally)
    int d = nt_dst(r);
    float alpha = 1.f/(1.f + __expf(-res_alpha[d]));
    float beta = 1.f - alpha;
    u16x4 rv = __builtin_nontemporal_load((const u16x4*)(resb + ((size_t)r*NN+n)*256 + l*4));
    float c0 = fmaxf(a0,0.f)*alpha + bf2f(rv.x)*beta;
    float c1 = fmaxf(a1,0.f)*alpha + bf2f(rv.y)*beta;
    float c2 = fmaxf(a2,0.f)*alpha + bf2f(rv.z)*beta;
    float c3 = fmaxf(a3,0.f)*alpha + bf2f(rv.w)*beta;

    if (r == 1 || r == 2){
        f32x4 o = {c0, c1, c2, c3};
        __builtin_nontemporal_store(o, (f32x4*)(out + ((size_t)r*NN+n)*256 + l*4));
    } else {
        int slot = (r == 0) ? 0 : 1;
        cbuf[slot][l*4+0] = c0; cbuf[slot][l*4+1] = c1;
        cbuf[slot][l*4+2] = c2; cbuf[slot][l*4+3] = c3;
        const float* ca0 = cross_attn;            // relation 0 weights
        const float* ca3 = cross_attn + 3*256;    // relation 3 weights
        float d0 = c0*ca0[l*4+0] + c1*ca0[l*4+1] + c2*ca0[l*4+2] + c3*ca0[l*4+3];
        float d3 = c0*ca3[l*4+0] + c1*ca3[l*4+1] + c2*ca3[l*4+2] + c3*ca3[l*4+3];
        #pragma unroll
        for (int msk = 1; msk < 8; msk <<= 1){
            d0 += __shfl_xor(d0, msk, 64);
            d3 += __shfl_xor(d3, msk, 64);
        }
        if ((l & 7) == 0){
            dots[slot*2+0][h] = d0;
            dots[slot*2+1][h] = d3;
        }
    }
    __syncthreads();
    if (r == 0 || r == 3){
        float g0 = (r == 0) ? dots[0][h] : dots[1][h];
        float g3 = (r == 0) ? dots[2][h] : dots[3][h];
        g0 = leaky(g0); g3 = leaky(g3);
        float mm = fmaxf(g0, g3);
        float w0 = __expf(g0-mm), w3 = __expf(g3-mm);
        float inv = 1.f/(w0+w3);
        w0 *= inv; w3 *= inv;
        f32x4 o;
        o.x = w0*cbuf[0][l*4+0] + w3*cbuf[1][l*4+0];
        o.y = w0*cbuf[0][l*4+1] + w3*cbuf[1][l*4+1];
        o.z = w0*cbuf[0][l*4+2] + w3*cbuf[1][l*4+2];
        o.w = w0*cbuf[0][l*4+3] + w3*cbuf[1][l*4+3];
        __builtin_nontemporal_store(o, (f32x4*)(out + ((size_t)r*NN+n)*256 + l*4));
    }
}

__global__ void k_relout(const float* __restrict__ rel_emb, const float* __restrict__ prop_W,
                         const float* __restrict__ prop_b, float* __restrict__ out){
    int r = blockIdx.x; int o = threadIdx.x;
    float acc = prop_b[r*256 + o];
    for (int i = 0; i < 64; i++) acc += rel_emb[r*64+i] * prop_W[(r*64+i)*256 + o];
    out[(size_t)4*NN*256 + r*256 + o] = acc;
}

extern "C" void kernel_launch(void* const* d_in, const int* in_sizes, int n_in,
                              void* d_out, int out_size, void* d_ws, size_t ws_size,
                              hipStream_t stream){
    const float* feat      = (const float*)d_in[0];
    const float* rel_emb   = (const float*)d_in[1];
    const float* node_W    = (const float*)d_in[2];
    const float* rel_W     = (const float*)d_in[3];
    const float* res_W     = (const float*)d_in[4];
    const float* res_b     = (const float*)d_in[5];
    const float* res_alpha = (const float*)d_in[6];
    const float* cross_attn= (const float*)d_in[7];
    const float* prop_W    = (const float*)d_in[8];
    const float* prop_b    = (const float*)d_in[9];
    const int* src_idx     = (const int*)d_in[10];
    const int* dst_idx     = (const int*)d_in[11];
    float* out = (float*)d_out;

    char* ws = (char*)d_ws;
    u32*   cnt     = (u32*)  (ws);                 //    800,000 B (4,NN)
    u32*   cnt2    = (u32*)  (ws + 800000);        //    800,000 B (4,NN)
    u32*   bsum    = (u32*)  (ws + 1600000);       //      4,096 B (4,256)
    u32*   row_ptr = (u32*)  (ws + 1604096);       //    800,016 B (4,NN+1)
    float* ra      = (float*)(ws + 2404112);       //      8,192 B (4,512)
    u16*   WcatS   = (u16*)  (ws + 2412304);       //  1,179,648 B (4,9,32,64,8) bf16
    float* e_comb  = (float*)(ws + 3591952);       // 12,800,000 B (4,NN,16) [src|dst]
    u32*   src_pack= (u32*)  (ws + 16391952);      //  3,200,000 B (4,NE)
    float* e_pack  = (float*)(ws + 19591952);      // 25,600,000 B (4,NE,8)
    u16*   fsrc    = (u16*)  (ws + 45191952);      //102,400,000 B (4,NN,256) bf16
    u16*   resb    = (u16*)  (ws + 147591952);     //102,400,000 B (4,NN,256) bf16
    // total: 249,991,952 B

    hipMemsetAsync(cnt, 0, 1604096, stream);  // cnt + cnt2 + bsum

    k_ra<<<4, 256, 0, stream>>>(rel_emb, rel_W, ra);
    k_wcat<<<(4*WCT*256)/256, 256, 0, stream>>>(node_W, res_W, ra, WcatS);
    dim3 gg((NN+63)/64, 4);
    k_gemm<<<gg, 256, 0, stream>>>(feat, WcatS, res_b, fsrc, resb, e_comb);

    dim3 geg((NE+255)/256, 4);
    k_count<<<geg, 256, 0, stream>>>(dst_idx, cnt);
    dim3 gsc((NN+255)/256, 4);
    k_scan1<<<gsc, 256, 0, stream>>>(cnt, bsum);
    k_scan2<<<4, 256, 0, stream>>>(bsum);
    k_scan3<<<gsc, 256, 0, stream>>>(cnt, bsum, row_ptr);
    k_scatter<<<geg, 256, 0, stream>>>(src_idx, dst_idx, e_comb, row_ptr, cnt2,
                                       src_pack, e_pack);
    k_aggx<<<NN, 256, 0, stream>>>(row_ptr, src_pack, e_pack, fsrc, resb,
                                   res_alpha, cross_attn, out);
    k_relout<<<4, 256, 0, stream>>>(rel_emb, prop_W, prop_b, out);
}

// Round 11
// 434.385 us; speedup vs baseline: 1.8516x; 1.0275x over previous
//
#include <hip/hip_runtime.h>
#include <hip/hip_bf16.h>
#include <stdint.h>

typedef unsigned int u32;
typedef unsigned short u16;
typedef short short8 __attribute__((ext_vector_type(8)));
typedef float f32x4 __attribute__((ext_vector_type(4)));
typedef unsigned short u16x4 __attribute__((ext_vector_type(4)));
typedef __attribute__((address_space(1))) const u32 gu32;
typedef __attribute__((address_space(3))) u32 lu32;

#define NN 50000
#define NE 200000
#define WCT 576     // 256 fsrc | 256 res | 8 e_src | 8 e_dst | 48 pad (cols of C)

__device__ __forceinline__ float leaky(float x){ return x >= 0.f ? x : 0.2f*x; }
__device__ __forceinline__ float bf2f(u16 u){ return __uint_as_float(((u32)u)<<16); }
__device__ __forceinline__ u16 f2bf(float f){            // RNE
    u32 u = __float_as_uint(f);
    u32 r = (u + 0x7fffu + ((u>>16)&1u)) >> 16;
    return (u16)r;
}
// pack 2 floats -> 2 bf16 (truncation) in ONE v_perm_b32
__device__ __forceinline__ u32 pack_bf2(float a, float b){
    return __builtin_amdgcn_perm(__float_as_uint(b), __float_as_uint(a), 0x07060302u);
}
__device__ __forceinline__ int nt_src(int r){ return (r==0)?0:((r==3)?2:1); }
__device__ __forceinline__ int nt_dst(int r){ return (r==1)?0:((r==2)?2:1); }

// ra[r][512] = rel_emb[r] @ rel_W[r]
__global__ void k_ra(const float* __restrict__ rel_emb, const float* __restrict__ rel_W,
                     float* __restrict__ ra){
    int r = blockIdx.x;
    for (int j = threadIdx.x; j < 512; j += blockDim.x){
        float acc = 0.f;
        for (int i = 0; i < 64; i++) acc += rel_emb[r*64+i] * rel_W[(r*64+i)*512 + j];
        ra[r*512 + j] = acc;
    }
}

// Assemble WcatS: chunk-transposed bf16 layout matching linear global_load_lds staging:
//   WcatS[((r*9+tile)*32 + kc)*512 + nrow*8 + off] = W^T[n=tile*64+nrow][k=kc*8+off]
__global__ void k_wcat(const float* __restrict__ node_W, const float* __restrict__ res_W,
                       const float* __restrict__ ra, u16* __restrict__ WcatS){
    int g = blockIdx.x*blockDim.x + threadIdx.x;
    if (g >= 4*WCT*256) return;
    int r = g/147456; int rem = g%147456;
    int tile = rem/16384; int rem2 = rem%16384;
    int kc = rem2/512; int rem3 = rem2%512;
    int nrow = rem3>>3; int off = rem3&7;
    int n = tile*64 + nrow;
    int k = kc*8 + off;
    int s = nt_src(r), d = nt_dst(r);
    float v;
    if (n < 256) v = node_W[(s*256+k)*256 + n];
    else if (n < 512) v = res_W[(d*256+k)*256 + (n-256)];
    else if (n < 520){ // e_src weights: node_W[s]·ra[h, D:]
        int h = n-512; float a = 0.f;
        for (int dd = 0; dd < 32; dd++) a += node_W[(s*256+k)*256 + h*32+dd] * ra[r*512 + h*64+32+dd];
        v = a;
    } else if (n < 528){ // e_dst weights: node_W[d]·ra[h, :D]
        int h = n-520; float a = 0.f;
        for (int dd = 0; dd < 32; dd++) a += node_W[(d*256+k)*256 + h*32+dd] * ra[r*512 + h*64+dd];
        v = a;
    } else v = 0.f;
    WcatS[g] = f2bf(v);
}

// MFMA GEMM, fat blocks: one 512-thread block = 128-row strip x ALL 576 N.
// A K-resident in registers; B async-staged via global_load_lds, double-buffered.
// Epilogue C-stage ALIASES the dead B buffer -> LDS = 64 KB, 2 blocks/CU (16 waves).
__launch_bounds__(512, 4)
__global__ void k_gemm(const float* __restrict__ feat, const u16* __restrict__ WcatS,
                       const float* __restrict__ res_b,
                       u16* __restrict__ fsrc, u16* __restrict__ resb,
                       float* __restrict__ e_comb){
    __shared__ uint4 lsB[4096];          // 2 x 32KB B double buffer (cst aliases dead half)
    const short8* lsB8 = (const short8*)lsB;

    int r = blockIdx.y;
    int row0 = blockIdx.x*128;
    const float* A = feat + (size_t)r*NN*256;
    const u16*   W = WcatS + (size_t)r*9*16384;

    int t = threadIdx.x;
    int w = t>>6, l = t&63;
    int wm = (w>>1)*32, wn = (w&1)*32;   // 8 waves: 4 row-bands x 2 col-halves
    int li = l & 15, lg = l >> 4;

    // ---- A fragments: direct global -> registers, K-resident (64 VGPR/lane)
    short8 afr[2][8];
    #pragma unroll
    for (int mt = 0; mt < 2; mt++){
        int grow = row0 + wm + mt*16 + li; if (grow > NN-1) grow = NN-1;
        const float* ap = A + (size_t)grow*256 + lg*8;
        #pragma unroll
        for (int kk = 0; kk < 8; kk++){
            f32x4 x = __builtin_nontemporal_load((const f32x4*)(ap + kk*32));
            f32x4 y = __builtin_nontemporal_load((const f32x4*)(ap + kk*32 + 4));
            short8 f;
            ((u32*)&f)[0] = pack_bf2(x.x, x.y);
            ((u32*)&f)[1] = pack_bf2(x.z, x.w);
            ((u32*)&f)[2] = pack_bf2(y.x, y.y);
            ((u32*)&f)[3] = pack_bf2(y.z, y.w);
            afr[mt][kk] = f;
        }
    }

    // ---- prologue: stage tile 0 into buf 0 (async direct-to-LDS); 4 chunks/thread
    #pragma unroll
    for (int i = 0; i < 4; i++){
        int chunk = i*512 + t;
        __builtin_amdgcn_global_load_lds((gu32*)(W + (size_t)chunk*8),
                                         (lu32*)((char*)lsB + chunk*16), 16, 0, 0);
    }
    __syncthreads();

    int d = nt_dst(r);
    int orow = t>>2, oq = t&3;           // 512 threads -> 128 rows x 4 quarters
    int ogrow = row0 + orow;
    size_t onidx = (size_t)r*NN + ogrow;

    for (int T = 0; T < 8; T++){
        int cur = T & 1;
        // issue async stage of tile T+1 into the other buffer (flies under MFMA)
        {
            const u16* tb = W + (size_t)(T+1)*16384;
            char* lb = (char*)lsB + (cur^1)*32768;
            #pragma unroll
            for (int i = 0; i < 4; i++){
                int chunk = i*512 + t;
                __builtin_amdgcn_global_load_lds((gu32*)(tb + (size_t)chunk*8),
                                                 (lu32*)(lb + chunk*16), 16, 0, 0);
            }
        }
        // compute tile T from buf[cur]
        f32x4 acc[2][2] = {};
        #pragma unroll
        for (int kk = 0; kk < 8; kk++){
            short8 bfr[2];
            #pragma unroll
            for (int nt = 0; nt < 2; nt++)
                bfr[nt] = lsB8[cur*2048 + (kk*4+lg)*64 + wn + nt*16 + li];
            #pragma unroll
            for (int mt = 0; mt < 2; mt++)
                #pragma unroll
                for (int nt = 0; nt < 2; nt++)
                    acc[mt][nt] = __builtin_amdgcn_mfma_f32_16x16x32_bf16(afr[mt][kk], bfr[nt], acc[mt][nt], 0,0,0);
        }
        float bias[2] = {0.f, 0.f};
        if (T >= 4){
            bias[0] = res_b[d*256 + (T-4)*64 + wn + li];
            bias[1] = res_b[d*256 + (T-4)*64 + wn + 16 + li];
        }
        __syncthreads();   // ALL waves done reading buf[cur] (cst aliases it); drains async loads
        u16* cst = (u16*)(lsB + (size_t)cur*2048);   // 128 rows x stride 72 = 18.4 KB <= 32 KB
        #pragma unroll
        for (int mt = 0; mt < 2; mt++)
            #pragma unroll
            for (int nt = 0; nt < 2; nt++)
                #pragma unroll
                for (int qq = 0; qq < 4; qq++)
                    cst[(wm + mt*16 + lg*4 + qq)*72 + wn + nt*16 + li] = f2bf(acc[mt][nt][qq] + bias[nt]);
        __syncthreads();   // cst visible to all
        if (ogrow < NN){
            u16* dst = (T < 4) ? (fsrc + onidx*256 + T*64) : (resb + onidx*256 + (T-4)*64);
            const uint4* src = (const uint4*)(cst + orow*72 + oq*16);
            uint4* dq = (uint4*)(dst + oq*16);
            dq[0] = src[0];
            dq[1] = src[1];
        }
        __syncthreads();   // cst reads done before next iter's async loads overwrite buf[cur]
    }

    // ---- tile 8: e-columns 512..527 (nrow 0..15 of tile 8, in buf 0) -> e_comb
    if (wn == 0){
        f32x4 acc[2] = {};
        #pragma unroll
        for (int kk = 0; kk < 8; kk++){
            short8 bfr = lsB8[(kk*4+lg)*64 + li];
            #pragma unroll
            for (int mt = 0; mt < 2; mt++)
                acc[mt] = __builtin_amdgcn_mfma_f32_16x16x32_bf16(afr[mt][kk], bfr, acc[mt], 0,0,0);
        }
        #pragma unroll
        for (int mt = 0; mt < 2; mt++)
            #pragma unroll
            for (int qq = 0; qq < 4; qq++){
                int row = row0 + wm + mt*16 + lg*4 + qq;
                if (row < NN)
                    e_comb[((size_t)r*NN + row)*16 + li] = acc[mt][qq];
            }
    }
}

// ---- CSR build: count -> hierarchical scan -> scatter ----

__global__ void k_count(const int* __restrict__ dst_idx, u32* __restrict__ cnt){
    int r = blockIdx.y; int e = blockIdx.x*256 + threadIdx.x;
    if (e >= NE) return;
    atomicAdd(&cnt[r*NN + dst_idx[r*NE+e]], 1u);
}

__global__ void k_scan1(const u32* __restrict__ cnt, u32* __restrict__ bsum){
    int r = blockIdx.y, b = blockIdx.x;
    int i = b*256 + threadIdx.x;
    u32 v = (i < NN) ? cnt[r*NN+i] : 0u;
    #pragma unroll
    for (int off = 1; off < 64; off <<= 1) v += __shfl_xor(v, off, 64);
    __shared__ u32 wsum[4];
    int lane = threadIdx.x & 63, w = threadIdx.x >> 6;
    if (lane == 0) wsum[w] = v;
    __syncthreads();
    if (threadIdx.x == 0) bsum[r*256 + b] = wsum[0]+wsum[1]+wsum[2]+wsum[3];
}

__device__ __forceinline__ u32 block_scan_incl(u32 v){
    __shared__ u32 wsum[4];
    int lane = threadIdx.x & 63, w = threadIdx.x >> 6;
    #pragma unroll
    for (int off = 1; off < 64; off <<= 1){
        u32 t = __shfl_up(v, off, 64);
        if (lane >= off) v += t;
    }
    if (lane == 63) wsum[w] = v;
    __syncthreads();
    u32 add = 0;
    #pragma unroll
    for (int k = 0; k < 4; k++) if (k < w) add += wsum[k];
    return v + add;
}

__global__ void k_scan2(u32* __restrict__ bsum){
    int r = blockIdx.x;
    u32 v = bsum[r*256 + threadIdx.x];
    u32 incl = block_scan_incl(v);
    bsum[r*256 + threadIdx.x] = incl - v;
}

__global__ void k_scan3(const u32* __restrict__ cnt, const u32* __restrict__ bsum,
                        u32* __restrict__ row_ptr){
    int r = blockIdx.y, b = blockIdx.x;
    int i = b*256 + threadIdx.x;
    u32 v = (i < NN) ? cnt[r*NN+i] : 0u;
    u32 incl = block_scan_incl(v);
    if (i < NN) row_ptr[r*(NN+1) + i + 1] = bsum[r*256 + b] + incl;
    if (b == 0 && threadIdx.x == 0) row_ptr[r*(NN+1)] = 0u;
}

// per edge: pos in dst bucket; payload = src + 8 PRE-EXPONENTIATED logits
// (exp without max-subtraction is safe: |logit| <~ 20 << 88 at this data scale)
__global__ void k_scatter(const int* __restrict__ src_idx, const int* __restrict__ dst_idx,
                          const float* __restrict__ e_comb,
                          const u32* __restrict__ row_ptr, u32* __restrict__ cnt2,
                          u32* __restrict__ src_pack, float* __restrict__ e_pack){
    int r = blockIdx.y; int e = blockIdx.x*256 + threadIdx.x;
    if (e >= NE) return;
    int s = src_idx[r*NE+e], d = dst_idx[r*NE+e];
    u32 pos = row_ptr[r*(NN+1)+d] + atomicAdd(&cnt2[r*NN+d], 1u);
    src_pack[r*NE + pos] = (u32)s;
    const f32x4* es = (const f32x4*)(e_comb + (size_t)(r*NN+s)*16);
    const f32x4* ed = (const f32x4*)(e_comb + (size_t)(r*NN+d)*16 + 8);
    f32x4 s0 = es[0], s1 = es[1], d0 = ed[0], d1 = ed[1];
    f32x4 w0, w1;
    w0.x = __expf(leaky(s0.x+d0.x)); w0.y = __expf(leaky(s0.y+d0.y));
    w0.z = __expf(leaky(s0.z+d0.z)); w0.w = __expf(leaky(s0.w+d0.w));
    w1.x = __expf(leaky(s1.x+d1.x)); w1.y = __expf(leaky(s1.y+d1.y));
    w1.z = __expf(leaky(s1.z+d1.z)); w1.w = __expf(leaky(s1.w+d1.w));
    f32x4* ep = (f32x4*)(e_pack + ((size_t)(r*NE)+pos)*8);
    ep[0] = w0; ep[1] = w1;
}

// Fused aggregation + residual gate + cross-attention. One block per node;
// wave w = relation w. e_pack holds exp(logit): phase 1 = plain sum,
// phase 2 weight = ex * inv_sh (no exp in the hot loop). Streaming data
// (resb in, out) uses non-temporal ops to keep L3 for the fsrc gathers.
__launch_bounds__(256)
__global__ void k_aggx(const u32* __restrict__ row_ptr, const u32* __restrict__ src_pack,
                       const float* __restrict__ e_pack, const u16* __restrict__ fsrc,
                       const u16* __restrict__ resb, const float* __restrict__ res_alpha,
                       const float* __restrict__ cross_attn, float* __restrict__ out){
    __shared__ float cbuf[2][256];   // conv rows of relations 0 and 3
    __shared__ float dots[4][8];     // [c0·ca0, c0·ca3, c3·ca0, c3·ca3][head]

    int n = blockIdx.x;
    int r = threadIdx.x >> 6;        // relation = wave id
    int l = threadIdx.x & 63;
    int h = l >> 3;

    u32 p0 = row_ptr[r*(NN+1)+n];
    u32 p1 = row_ptr[r*(NN+1)+n+1];
    int deg = (int)(p1 - p0);

    // phase 1: plain sum of pre-exponentiated weights
    float s = 0.f;
    for (int i = (l>>3); i < deg; i += 8)
        s += e_pack[((size_t)(r*NE) + p0 + i)*8 + (l&7)];
    #pragma unroll
    for (int msk = 8; msk < 64; msk <<= 1)
        s += __shfl_xor(s, msk, 64);
    float sh = __shfl(s, h, 64);
    float inv_sh = (deg > 0) ? 1.0f / sh : 0.f;

    // phase 2: gather-accumulate; src preloaded + shfl-broadcast, 4-way unroll
    float a0=0.f, a1=0.f, a2=0.f, a3=0.f;
    const size_t ebase = (size_t)r*NE + p0;
    const u16* fbase = fsrc + (size_t)r*NN*256;
    for (int base = 0; base < deg; base += 64){
        int rem = deg - base; if (rem > 64) rem = 64;
        u32 my_src = 0;
        if (l < rem) my_src = src_pack[ebase + base + l];
        int i = 0;
        for (; i+4 <= rem; i += 4){
            u32 s0 = __shfl(my_src, i, 64);
            u32 s1 = __shfl(my_src, i+1, 64);
            u32 s2 = __shfl(my_src, i+2, 64);
            u32 s3 = __shfl(my_src, i+3, 64);
            float ex0 = e_pack[(ebase + base + i)*8 + h];
            float ex1 = e_pack[(ebase + base + i + 1)*8 + h];
            float ex2 = e_pack[(ebase + base + i + 2)*8 + h];
            float ex3 = e_pack[(ebase + base + i + 3)*8 + h];
            ushort4 f0 = *(const ushort4*)(fbase + (size_t)s0*256 + l*4);
            ushort4 f1 = *(const ushort4*)(fbase + (size_t)s1*256 + l*4);
            ushort4 f2 = *(const ushort4*)(fbase + (size_t)s2*256 + l*4);
            ushort4 f3 = *(const ushort4*)(fbase + (size_t)s3*256 + l*4);
            float w0 = ex0*inv_sh, w1 = ex1*inv_sh, w2 = ex2*inv_sh, w3 = ex3*inv_sh;
            a0 += bf2f(f0.x)*w0 + bf2f(f1.x)*w1 + bf2f(f2.x)*w2 + bf2f(f3.x)*w3;
            a1 += bf2f(f0.y)*w0 + bf2f(f1.y)*w1 + bf2f(f2.y)*w2 + bf2f(f3.y)*w3;
            a2 += bf2f(f0.z)*w0 + bf2f(f1.z)*w1 + bf2f(f2.z)*w2 + bf2f(f3.z)*w3;
            a3 += bf2f(f0.w)*w0 + bf2f(f1.w)*w1 + bf2f(f2.w)*w2 + bf2f(f3.w)*w3;
        }
        for (; i < rem; i++){
            u32 s0 = __shfl(my_src, i, 64);
            float w0 = e_pack[(ebase + base + i)*8 + h]*inv_sh;
            ushort4 f0 = *(const ushort4*)(fbase + (size_t)s0*256 + l*4);
            a0 += bf2f(f0.x)*w0; a1 += bf2f(f0.y)*w0; a2 += bf2f(f0.z)*w0; a3 += bf2f(f0.w)*w0;
        }
    }

    // residual gate (resb streamed non-temporally)
    int d = nt_dst(r);
    float alpha = 1.f/(1.f + __expf(-res_alpha[d]));
    float beta = 1.f - alpha;
    u16x4 rv = __builtin_nontemporal_load((const u16x4*)(resb + ((size_t)r*NN+n)*256 + l*4));
    float c0 = fmaxf(a0,0.f)*alpha + bf2f(rv.x)*beta;
    float c1 = fmaxf(a1,0.f)*alpha + bf2f(rv.y)*beta;
    float c2 = fmaxf(a2,0.f)*alpha + bf2f(rv.z)*beta;
    float c3 = fmaxf(a3,0.f)*alpha + bf2f(rv.w)*beta;

    if (r == 1 || r == 2){
        f32x4 o = {c0, c1, c2, c3};
        __builtin_nontemporal_store(o, (f32x4*)(out + ((size_t)r*NN+n)*256 + l*4));
    } else {
        int slot = (r == 0) ? 0 : 1;
        cbuf[slot][l*4+0] = c0; cbuf[slot][l*4+1] = c1;
        cbuf[slot][l*4+2] = c2; cbuf[slot][l*4+3] = c3;
        const float* ca0 = cross_attn;            // relation 0 weights
        const float* ca3 = cross_attn + 3*256;    // relation 3 weights
        float d0 = c0*ca0[l*4+0] + c1*ca0[l*4+1] + c2*ca0[l*4+2] + c3*ca0[l*4+3];
        float d3 = c0*ca3[l*4+0] + c1*ca3[l*4+1] + c2*ca3[l*4+2] + c3*ca3[l*4+3];
        #pragma unroll
        for (int msk = 1; msk < 8; msk <<= 1){
            d0 += __shfl_xor(d0, msk, 64);
            d3 += __shfl_xor(d3, msk, 64);
        }
        if ((l & 7) == 0){
            dots[slot*2+0][h] = d0;
            dots[slot*2+1][h] = d3;
        }
    }
    __syncthreads();
    if (r == 0 || r == 3){
        float g0 = (r == 0) ? dots[0][h] : dots[1][h];
        float g3 = (r == 0) ? dots[2][h] : dots[3][h];
        g0 = leaky(g0); g3 = leaky(g3);
        float mm = fmaxf(g0, g3);
        float w0 = __expf(g0-mm), w3 = __expf(g3-mm);
        float inv = 1.f/(w0+w3);
        w0 *= inv; w3 *= inv;
        f32x4 o;
        o.x = w0*cbuf[0][l*4+0] + w3*cbuf[1][l*4+0];
        o.y = w0*cbuf[0][l*4+1] + w3*cbuf[1][l*4+1];
        o.z = w0*cbuf[0][l*4+2] + w3*cbuf[1][l*4+2];
        o.w = w0*cbuf[0][l*4+3] + w3*cbuf[1][l*4+3];
        __builtin_nontemporal_store(o, (f32x4*)(out + ((size_t)r*NN+n)*256 + l*4));
    }
}

__global__ void k_relout(const float* __restrict__ rel_emb, const float* __restrict__ prop_W,
                         const float* __restrict__ prop_b, float* __restrict__ out){
    int r = blockIdx.x; int o = threadIdx.x;
    float acc = prop_b[r*256 + o];
    for (int i = 0; i < 64; i++) acc += rel_emb[r*64+i] * prop_W[(r*64+i)*256 + o];
    out[(size_t)4*NN*256 + r*256 + o] = acc;
}

extern "C" void kernel_launch(void* const* d_in, const int* in_sizes, int n_in,
                              void* d_out, int out_size, void* d_ws, size_t ws_size,
                              hipStream_t stream){
    const float* feat      = (const float*)d_in[0];
    const float* rel_emb   = (const float*)d_in[1];
    const float* node_W    = (const float*)d_in[2];
    const float* rel_W     = (const float*)d_in[3];
    const float* res_W     = (const float*)d_in[4];
    const float* res_b     = (const float*)d_in[5];
    const float* res_alpha = (const float*)d_in[6];
    const float* cross_attn= (const float*)d_in[7];
    const float* prop_W    = (const float*)d_in[8];
    const float* prop_b    = (const float*)d_in[9];
    const int* src_idx     = (const int*)d_in[10];
    const int* dst_idx     = (const int*)d_in[11];
    float* out = (float*)d_out;

    char* ws = (char*)d_ws;
    u32*   cnt     = (u32*)  (ws);                 //    800,000 B (4,NN)
    u32*   cnt2    = (u32*)  (ws + 800000);        //    800,000 B (4,NN)
    u32*   bsum    = (u32*)  (ws + 1600000);       //      4,096 B (4,256)
    u32*   row_ptr = (u32*)  (ws + 1604096);       //    800,016 B (4,NN+1)
    float* ra      = (float*)(ws + 2404112);       //      8,192 B (4,512)
    u16*   WcatS   = (u16*)  (ws + 2412304);       //  1,179,648 B (4,9,32,64,8) bf16
    float* e_comb  = (float*)(ws + 3591952);       // 12,800,000 B (4,NN,16) [src|dst]
    u32*   src_pack= (u32*)  (ws + 16391952);      //  3,200,000 B (4,NE)
    float* e_pack  = (float*)(ws + 19591952);      // 25,600,000 B (4,NE,8)
    u16*   fsrc    = (u16*)  (ws + 45191952);      //102,400,000 B (4,NN,256) bf16
    u16*   resb    = (u16*)  (ws + 147591952);     //102,400,000 B (4,NN,256) bf16
    // total: 249,991,952 B

    hipMemsetAsync(cnt, 0, 1604096, stream);  // cnt + cnt2 + bsum

    k_ra<<<4, 256, 0, stream>>>(rel_emb, rel_W, ra);
    k_wcat<<<(4*WCT*256)/256, 256, 0, stream>>>(node_W, res_W, ra, WcatS);
    dim3 gg((NN+127)/128, 4);
    k_gemm<<<gg, 512, 0, stream>>>(feat, WcatS, res_b, fsrc, resb, e_comb);

    dim3 geg((NE+255)/256, 4);
    k_count<<<geg, 256, 0, stream>>>(dst_idx, cnt);
    dim3 gsc((NN+255)/256, 4);
    k_scan1<<<gsc, 256, 0, stream>>>(cnt, bsum);
    k_scan2<<<4, 256, 0, stream>>>(bsum);
    k_scan3<<<gsc, 256, 0, stream>>>(cnt, bsum, row_ptr);
    k_scatter<<<geg, 256, 0, stream>>>(src_idx, dst_idx, e_comb, row_ptr, cnt2,
                                       src_pack, e_pack);
    k_aggx<<<NN, 256, 0, stream>>>(row_ptr, src_pack, e_pack, fsrc, resb,
                                   res_alpha, cross_attn, out);
    k_relout<<<4, 256, 0, stream>>>(rel_emb, prop_W, prop_b, out);
}

// Round 12
// 428.068 us; speedup vs baseline: 1.8790x; 1.0148x over previous
//
#include <hip/hip_runtime.h>
#include <hip/hip_bf16.h>
#include <stdint.h>

typedef unsigned int u32;
typedef unsigned short u16;
typedef short short8 __attribute__((ext_vector_type(8)));
typedef float f32x4 __attribute__((ext_vector_type(4)));
typedef unsigned short u16x4 __attribute__((ext_vector_type(4)));
typedef __attribute__((address_space(1))) const u32 gu32;
typedef __attribute__((address_space(3))) u32 lu32;

#define NN 50000
#define NE 200000
#define WCT 576     // 256 fsrc | 256 res | 8 e_src | 8 e_dst | 48 pad (cols of C)

__device__ __forceinline__ float leaky(float x){ return x >= 0.f ? x : 0.2f*x; }
__device__ __forceinline__ float bf2f(u16 u){ return __uint_as_float(((u32)u)<<16); }
__device__ __forceinline__ u16 f2bf(float f){            // RNE
    u32 u = __float_as_uint(f);
    u32 r = (u + 0x7fffu + ((u>>16)&1u)) >> 16;
    return (u16)r;
}
// pack 2 floats -> 2 bf16 (truncation) in ONE v_perm_b32
__device__ __forceinline__ u32 pack_bf2(float a, float b){
    return __builtin_amdgcn_perm(__float_as_uint(b), __float_as_uint(a), 0x07060302u);
}
__device__ __forceinline__ int nt_src(int r){ return (r==0)?0:((r==3)?2:1); }
__device__ __forceinline__ int nt_dst(int r){ return (r==1)?0:((r==2)?2:1); }

// ra[r][512] = rel_emb[r] @ rel_W[r]
__global__ void k_ra(const float* __restrict__ rel_emb, const float* __restrict__ rel_W,
                     float* __restrict__ ra){
    int r = blockIdx.x;
    for (int j = threadIdx.x; j < 512; j += blockDim.x){
        float acc = 0.f;
        for (int i = 0; i < 64; i++) acc += rel_emb[r*64+i] * rel_W[(r*64+i)*512 + j];
        ra[r*512 + j] = acc;
    }
}

// Assemble WcatS: chunk-transposed bf16 layout matching linear global_load_lds staging:
//   WcatS[((r*9+tile)*32 + kc)*512 + nrow*8 + off] = W^T[n=tile*64+nrow][k=kc*8+off]
__global__ void k_wcat(const float* __restrict__ node_W, const float* __restrict__ res_W,
                       const float* __restrict__ ra, u16* __restrict__ WcatS){
    int g = blockIdx.x*blockDim.x + threadIdx.x;
    if (g >= 4*WCT*256) return;
    int r = g/147456; int rem = g%147456;
    int tile = rem/16384; int rem2 = rem%16384;
    int kc = rem2/512; int rem3 = rem2%512;
    int nrow = rem3>>3; int off = rem3&7;
    int n = tile*64 + nrow;
    int k = kc*8 + off;
    int s = nt_src(r), d = nt_dst(r);
    float v;
    if (n < 256) v = node_W[(s*256+k)*256 + n];
    else if (n < 512) v = res_W[(d*256+k)*256 + (n-256)];
    else if (n < 520){ // e_src weights: node_W[s]·ra[h, D:]
        int h = n-512; float a = 0.f;
        for (int dd = 0; dd < 32; dd++) a += node_W[(s*256+k)*256 + h*32+dd] * ra[r*512 + h*64+32+dd];
        v = a;
    } else if (n < 528){ // e_dst weights: node_W[d]·ra[h, :D]
        int h = n-520; float a = 0.f;
        for (int dd = 0; dd < 32; dd++) a += node_W[(d*256+k)*256 + h*32+dd] * ra[r*512 + h*64+dd];
        v = a;
    } else v = 0.f;
    WcatS[g] = f2bf(v);
}

// MFMA GEMM, fat blocks: one 512-thread block = 128-row strip x ALL 576 N.
// A K-resident in registers; B async-staged via global_load_lds, double-buffered.
// Epilogue C-stage ALIASES the dead B buffer -> LDS = 64 KB, 2 blocks/CU (16 waves).
__launch_bounds__(512, 4)
__global__ void k_gemm(const float* __restrict__ feat, const u16* __restrict__ WcatS,
                       const float* __restrict__ res_b,
                       u16* __restrict__ fsrc, u16* __restrict__ resb,
                       float* __restrict__ e_comb){
    __shared__ uint4 lsB[4096];          // 2 x 32KB B double buffer (cst aliases dead half)
    const short8* lsB8 = (const short8*)lsB;

    int r = blockIdx.y;
    int row0 = blockIdx.x*128;
    const float* A = feat + (size_t)r*NN*256;
    const u16*   W = WcatS + (size_t)r*9*16384;

    int t = threadIdx.x;
    int w = t>>6, l = t&63;
    int wm = (w>>1)*32, wn = (w&1)*32;   // 8 waves: 4 row-bands x 2 col-halves
    int li = l & 15, lg = l >> 4;

    // ---- A fragments: direct global -> registers, K-resident (64 VGPR/lane)
    short8 afr[2][8];
    #pragma unroll
    for (int mt = 0; mt < 2; mt++){
        int grow = row0 + wm + mt*16 + li; if (grow > NN-1) grow = NN-1;
        const float* ap = A + (size_t)grow*256 + lg*8;
        #pragma unroll
        for (int kk = 0; kk < 8; kk++){
            f32x4 x = __builtin_nontemporal_load((const f32x4*)(ap + kk*32));
            f32x4 y = __builtin_nontemporal_load((const f32x4*)(ap + kk*32 + 4));
            short8 f;
            ((u32*)&f)[0] = pack_bf2(x.x, x.y);
            ((u32*)&f)[1] = pack_bf2(x.z, x.w);
            ((u32*)&f)[2] = pack_bf2(y.x, y.y);
            ((u32*)&f)[3] = pack_bf2(y.z, y.w);
            afr[mt][kk] = f;
        }
    }

    // ---- prologue: stage tile 0 into buf 0 (async direct-to-LDS); 4 chunks/thread
    #pragma unroll
    for (int i = 0; i < 4; i++){
        int chunk = i*512 + t;
        __builtin_amdgcn_global_load_lds((gu32*)(W + (size_t)chunk*8),
                                         (lu32*)((char*)lsB + chunk*16), 16, 0, 0);
    }
    __syncthreads();

    int d = nt_dst(r);
    int orow = t>>2, oq = t&3;           // 512 threads -> 128 rows x 4 quarters
    int ogrow = row0 + orow;
    size_t onidx = (size_t)r*NN + ogrow;

    for (int T = 0; T < 8; T++){
        int cur = T & 1;
        // issue async stage of tile T+1 into the other buffer (flies under MFMA)
        {
            const u16* tb = W + (size_t)(T+1)*16384;
            char* lb = (char*)lsB + (cur^1)*32768;
            #pragma unroll
            for (int i = 0; i < 4; i++){
                int chunk = i*512 + t;
                __builtin_amdgcn_global_load_lds((gu32*)(tb + (size_t)chunk*8),
                                                 (lu32*)(lb + chunk*16), 16, 0, 0);
            }
        }
        // compute tile T from buf[cur]
        f32x4 acc[2][2] = {};
        #pragma unroll
        for (int kk = 0; kk < 8; kk++){
            short8 bfr[2];
            #pragma unroll
            for (int nt = 0; nt < 2; nt++)
                bfr[nt] = lsB8[cur*2048 + (kk*4+lg)*64 + wn + nt*16 + li];
            #pragma unroll
            for (int mt = 0; mt < 2; mt++)
                #pragma unroll
                for (int nt = 0; nt < 2; nt++)
                    acc[mt][nt] = __builtin_amdgcn_mfma_f32_16x16x32_bf16(afr[mt][kk], bfr[nt], acc[mt][nt], 0,0,0);
        }
        float bias[2] = {0.f, 0.f};
        if (T >= 4){
            bias[0] = res_b[d*256 + (T-4)*64 + wn + li];
            bias[1] = res_b[d*256 + (T-4)*64 + wn + 16 + li];
        }
        __syncthreads();   // ALL waves done reading buf[cur] (cst aliases it); drains async loads
        u16* cst = (u16*)(lsB + (size_t)cur*2048);   // 128 rows x stride 72 = 18.4 KB <= 32 KB
        #pragma unroll
        for (int mt = 0; mt < 2; mt++)
            #pragma unroll
            for (int nt = 0; nt < 2; nt++)
                #pragma unroll
                for (int qq = 0; qq < 4; qq++)
                    cst[(wm + mt*16 + lg*4 + qq)*72 + wn + nt*16 + li] = f2bf(acc[mt][nt][qq] + bias[nt]);
        __syncthreads();   // cst visible to all
        if (ogrow < NN){
            u16* dst = (T < 4) ? (fsrc + onidx*256 + T*64) : (resb + onidx*256 + (T-4)*64);
            const uint4* src = (const uint4*)(cst + orow*72 + oq*16);
            uint4* dq = (uint4*)(dst + oq*16);
            dq[0] = src[0];
            dq[1] = src[1];
        }
        __syncthreads();   // cst reads done before next iter's async loads overwrite buf[cur]
    }

    // ---- tile 8: e-columns 512..527 (nrow 0..15 of tile 8, in buf 0) -> e_comb
    if (wn == 0){
        f32x4 acc[2] = {};
        #pragma unroll
        for (int kk = 0; kk < 8; kk++){
            short8 bfr = lsB8[(kk*4+lg)*64 + li];
            #pragma unroll
            for (int mt = 0; mt < 2; mt++)
                acc[mt] = __builtin_amdgcn_mfma_f32_16x16x32_bf16(afr[mt][kk], bfr, acc[mt], 0,0,0);
        }
        #pragma unroll
        for (int mt = 0; mt < 2; mt++)
            #pragma unroll
            for (int qq = 0; qq < 4; qq++){
                int row = row0 + wm + mt*16 + lg*4 + qq;
                if (row < NN)
                    e_comb[((size_t)r*NN + row)*16 + li] = acc[mt][qq];
            }
    }
}

// ---- CSR build: count -> hierarchical scan -> scatter ----

__global__ void k_count(const int* __restrict__ dst_idx, u32* __restrict__ cnt){
    int r = blockIdx.y; int e = blockIdx.x*256 + threadIdx.x;
    if (e >= NE) return;
    atomicAdd(&cnt[r*NN + dst_idx[r*NE+e]], 1u);
}

__global__ void k_scan1(const u32* __restrict__ cnt, u32* __restrict__ bsum){
    int r = blockIdx.y, b = blockIdx.x;
    int i = b*256 + threadIdx.x;
    u32 v = (i < NN) ? cnt[r*NN+i] : 0u;
    #pragma unroll
    for (int off = 1; off < 64; off <<= 1) v += __shfl_xor(v, off, 64);
    __shared__ u32 wsum[4];
    int lane = threadIdx.x & 63, w = threadIdx.x >> 6;
    if (lane == 0) wsum[w] = v;
    __syncthreads();
    if (threadIdx.x == 0) bsum[r*256 + b] = wsum[0]+wsum[1]+wsum[2]+wsum[3];
}

__device__ __forceinline__ u32 block_scan_incl(u32 v){
    __shared__ u32 wsum[4];
    int lane = threadIdx.x & 63, w = threadIdx.x >> 6;
    #pragma unroll
    for (int off = 1; off < 64; off <<= 1){
        u32 t = __shfl_up(v, off, 64);
        if (lane >= off) v += t;
    }
    if (lane == 63) wsum[w] = v;
    __syncthreads();
    u32 add = 0;
    #pragma unroll
    for (int k = 0; k < 4; k++) if (k < w) add += wsum[k];
    return v + add;
}

__global__ void k_scan2(u32* __restrict__ bsum){
    int r = blockIdx.x;
    u32 v = bsum[r*256 + threadIdx.x];
    u32 incl = block_scan_incl(v);
    bsum[r*256 + threadIdx.x] = incl - v;
}

__global__ void k_scan3(const u32* __restrict__ cnt, const u32* __restrict__ bsum,
                        u32* __restrict__ row_ptr){
    int r = blockIdx.y, b = blockIdx.x;
    int i = b*256 + threadIdx.x;
    u32 v = (i < NN) ? cnt[r*NN+i] : 0u;
    u32 incl = block_scan_incl(v);
    if (i < NN) row_ptr[r*(NN+1) + i + 1] = bsum[r*256 + b] + incl;
    if (b == 0 && threadIdx.x == 0) row_ptr[r*(NN+1)] = 0u;
}

// per edge: pos in dst bucket; payload = src + 8 PRE-EXPONENTIATED logits
// (exp without max-subtraction is safe: |logit| <~ 20 << 88 at this data scale)
__global__ void k_scatter(const int* __restrict__ src_idx, const int* __restrict__ dst_idx,
                          const float* __restrict__ e_comb,
                          const u32* __restrict__ row_ptr, u32* __restrict__ cnt2,
                          u32* __restrict__ src_pack, float* __restrict__ e_pack){
    int r = blockIdx.y; int e = blockIdx.x*256 + threadIdx.x;
    if (e >= NE) return;
    int s = src_idx[r*NE+e], d = dst_idx[r*NE+e];
    u32 pos = row_ptr[r*(NN+1)+d] + atomicAdd(&cnt2[r*NN+d], 1u);
    src_pack[r*NE + pos] = (u32)s;
    const f32x4* es = (const f32x4*)(e_comb + (size_t)(r*NN+s)*16);
    const f32x4* ed = (const f32x4*)(e_comb + (size_t)(r*NN+d)*16 + 8);
    f32x4 s0 = es[0], s1 = es[1], d0 = ed[0], d1 = ed[1];
    f32x4 w0, w1;
    w0.x = __expf(leaky(s0.x+d0.x)); w0.y = __expf(leaky(s0.y+d0.y));
    w0.z = __expf(leaky(s0.z+d0.z)); w0.w = __expf(leaky(s0.w+d0.w));
    w1.x = __expf(leaky(s1.x+d1.x)); w1.y = __expf(leaky(s1.y+d1.y));
    w1.z = __expf(leaky(s1.z+d1.z)); w1.w = __expf(leaky(s1.w+d1.w));
    f32x4* ep = (f32x4*)(e_pack + ((size_t)(r*NE)+pos)*8);
    ep[0] = w0; ep[1] = w1;
}

// Shared aggregation core: per (node, relation) wave -> conv row (c0..c3 per lane).
// e_pack holds exp(logit): phase 1 = plain sum; phase 2 weight = ex*inv_sh.
__device__ __forceinline__ void agg_core(int n, int r, int l, int h,
                                         const u32* __restrict__ row_ptr,
                                         const u32* __restrict__ src_pack,
                                         const float* __restrict__ e_pack,
                                         const u16* __restrict__ fsrc,
                                         const u16* __restrict__ resb,
                                         const float* __restrict__ res_alpha,
                                         float& c0, float& c1, float& c2, float& c3){
    u32 p0 = row_ptr[r*(NN+1)+n];
    u32 p1 = row_ptr[r*(NN+1)+n+1];
    int deg = (int)(p1 - p0);

    // phase 1: plain sum of pre-exponentiated weights
    float s = 0.f;
    for (int i = (l>>3); i < deg; i += 8)
        s += e_pack[((size_t)(r*NE) + p0 + i)*8 + (l&7)];
    #pragma unroll
    for (int msk = 8; msk < 64; msk <<= 1)
        s += __shfl_xor(s, msk, 64);
    float sh = __shfl(s, h, 64);
    float inv_sh = (deg > 0) ? 1.0f / sh : 0.f;

    // phase 2: gather-accumulate; src preloaded + shfl-broadcast, 4-way unroll
    float a0=0.f, a1=0.f, a2=0.f, a3=0.f;
    const size_t ebase = (size_t)r*NE + p0;
    const u16* fbase = fsrc + (size_t)r*NN*256;
    for (int base = 0; base < deg; base += 64){
        int rem = deg - base; if (rem > 64) rem = 64;
        u32 my_src = 0;
        if (l < rem) my_src = src_pack[ebase + base + l];
        int i = 0;
        for (; i+4 <= rem; i += 4){
            u32 s0 = __shfl(my_src, i, 64);
            u32 s1 = __shfl(my_src, i+1, 64);
            u32 s2 = __shfl(my_src, i+2, 64);
            u32 s3 = __shfl(my_src, i+3, 64);
            float ex0 = e_pack[(ebase + base + i)*8 + h];
            float ex1 = e_pack[(ebase + base + i + 1)*8 + h];
            float ex2 = e_pack[(ebase + base + i + 2)*8 + h];
            float ex3 = e_pack[(ebase + base + i + 3)*8 + h];
            ushort4 f0 = *(const ushort4*)(fbase + (size_t)s0*256 + l*4);
            ushort4 f1 = *(const ushort4*)(fbase + (size_t)s1*256 + l*4);
            ushort4 f2 = *(const ushort4*)(fbase + (size_t)s2*256 + l*4);
            ushort4 f3 = *(const ushort4*)(fbase + (size_t)s3*256 + l*4);
            float w0 = ex0*inv_sh, w1 = ex1*inv_sh, w2 = ex2*inv_sh, w3 = ex3*inv_sh;
            a0 += bf2f(f0.x)*w0 + bf2f(f1.x)*w1 + bf2f(f2.x)*w2 + bf2f(f3.x)*w3;
            a1 += bf2f(f0.y)*w0 + bf2f(f1.y)*w1 + bf2f(f2.y)*w2 + bf2f(f3.y)*w3;
            a2 += bf2f(f0.z)*w0 + bf2f(f1.z)*w1 + bf2f(f2.z)*w2 + bf2f(f3.z)*w3;
            a3 += bf2f(f0.w)*w0 + bf2f(f1.w)*w1 + bf2f(f2.w)*w2 + bf2f(f3.w)*w3;
        }
        for (; i < rem; i++){
            u32 s0 = __shfl(my_src, i, 64);
            float w0 = e_pack[(ebase + base + i)*8 + h]*inv_sh;
            ushort4 f0 = *(const ushort4*)(fbase + (size_t)s0*256 + l*4);
            a0 += bf2f(f0.x)*w0; a1 += bf2f(f0.y)*w0; a2 += bf2f(f0.z)*w0; a3 += bf2f(f0.w)*w0;
        }
    }

    int d = nt_dst(r);
    float alpha = 1.f/(1.f + __expf(-res_alpha[d]));
    float beta = 1.f - alpha;
    u16x4 rv = __builtin_nontemporal_load((const u16x4*)(resb + ((size_t)r*NN+n)*256 + l*4));
    c0 = fmaxf(a0,0.f)*alpha + bf2f(rv.x)*beta;
    c1 = fmaxf(a1,0.f)*alpha + bf2f(rv.y)*beta;
    c2 = fmaxf(a2,0.f)*alpha + bf2f(rv.z)*beta;
    c3 = fmaxf(a3,0.f)*alpha + bf2f(rv.w)*beta;
}

// Pass 1: relations 1,2 (no cross-attention). Working set ~204 MB -> L3-resident.
__launch_bounds__(128)
__global__ void k_agg12(const u32* __restrict__ row_ptr, const u32* __restrict__ src_pack,
                        const float* __restrict__ e_pack, const u16* __restrict__ fsrc,
                        const u16* __restrict__ resb, const float* __restrict__ res_alpha,
                        float* __restrict__ out){
    int n = blockIdx.x;
    int r = 1 + (threadIdx.x >> 6);   // 1 or 2
    int l = threadIdx.x & 63;
    int h = l >> 3;
    float c0, c1, c2, c3;
    agg_core(n, r, l, h, row_ptr, src_pack, e_pack, fsrc, resb, res_alpha, c0, c1, c2, c3);
    f32x4 o = {c0, c1, c2, c3};
    __builtin_nontemporal_store(o, (f32x4*)(out + ((size_t)r*NN+n)*256 + l*4));
}

// Pass 2: relations 0,3 + fused cross-attention (dst ntype 1 group).
__launch_bounds__(128)
__global__ void k_aggx03(const u32* __restrict__ row_ptr, const u32* __restrict__ src_pack,
                         const float* __restrict__ e_pack, const u16* __restrict__ fsrc,
                         const u16* __restrict__ resb, const float* __restrict__ res_alpha,
                         const float* __restrict__ cross_attn, float* __restrict__ out){
    __shared__ float cbuf[2][256];   // conv rows of relations 0 and 3
    __shared__ float dots[4][8];     // [c0·ca0, c0·ca3, c3·ca0, c3·ca3][head]

    int n = blockIdx.x;
    int w = threadIdx.x >> 6;        // 0 or 1
    int r = w ? 3 : 0;
    int l = threadIdx.x & 63;
    int h = l >> 3;
    float c0, c1, c2, c3;
    agg_core(n, r, l, h, row_ptr, src_pack, e_pack, fsrc, resb, res_alpha, c0, c1, c2, c3);

    int slot = w;
    cbuf[slot][l*4+0] = c0; cbuf[slot][l*4+1] = c1;
    cbuf[slot][l*4+2] = c2; cbuf[slot][l*4+3] = c3;
    const float* ca0 = cross_attn;            // relation 0 weights
    const float* ca3 = cross_attn + 3*256;    // relation 3 weights
    float d0 = c0*ca0[l*4+0] + c1*ca0[l*4+1] + c2*ca0[l*4+2] + c3*ca0[l*4+3];
    float d3 = c0*ca3[l*4+0] + c1*ca3[l*4+1] + c2*ca3[l*4+2] + c3*ca3[l*4+3];
    #pragma unroll
    for (int msk = 1; msk < 8; msk <<= 1){
        d0 += __shfl_xor(d0, msk, 64);
        d3 += __shfl_xor(d3, msk, 64);
    }
    if ((l & 7) == 0){
        dots[slot*2+0][h] = d0;
        dots[slot*2+1][h] = d3;
    }
    __syncthreads();
    // out r uses cross_attn[r]: logits = (conv0·ca_r, conv3·ca_r) per head
    float g0 = (r == 0) ? dots[0][h] : dots[1][h];
    float g3 = (r == 0) ? dots[2][h] : dots[3][h];
    g0 = leaky(g0); g3 = leaky(g3);
    float mm = fmaxf(g0, g3);
    float w0 = __expf(g0-mm), w3 = __expf(g3-mm);
    float inv = 1.f/(w0+w3);
    w0 *= inv; w3 *= inv;
    f32x4 o;
    o.x = w0*cbuf[0][l*4+0] + w3*cbuf[1][l*4+0];
    o.y = w0*cbuf[0][l*4+1] + w3*cbuf[1][l*4+1];
    o.z = w0*cbuf[0][l*4+2] + w3*cbuf[1][l*4+2];
    o.w = w0*cbuf[0][l*4+3] + w3*cbuf[1][l*4+3];
    __builtin_nontemporal_store(o, (f32x4*)(out + ((size_t)r*NN+n)*256 + l*4));
}

__global__ void k_relout(const float* __restrict__ rel_emb, const float* __restrict__ prop_W,
                         const float* __restrict__ prop_b, float* __restrict__ out){
    int r = blockIdx.x; int o = threadIdx.x;
    float acc = prop_b[r*256 + o];
    for (int i = 0; i < 64; i++) acc += rel_emb[r*64+i] * prop_W[(r*64+i)*256 + o];
    out[(size_t)4*NN*256 + r*256 + o] = acc;
}

extern "C" void kernel_launch(void* const* d_in, const int* in_sizes, int n_in,
                              void* d_out, int out_size, void* d_ws, size_t ws_size,
                              hipStream_t stream){
    const float* feat      = (const float*)d_in[0];
    const float* rel_emb   = (const float*)d_in[1];
    const float* node_W    = (const float*)d_in[2];
    const float* rel_W     = (const float*)d_in[3];
    const float* res_W     = (const float*)d_in[4];
    const float* res_b     = (const float*)d_in[5];
    const float* res_alpha = (const float*)d_in[6];
    const float* cross_attn= (const float*)d_in[7];
    const float* prop_W    = (const float*)d_in[8];
    const float* prop_b    = (const float*)d_in[9];
    const int* src_idx     = (const int*)d_in[10];
    const int* dst_idx     = (const int*)d_in[11];
    float* out = (float*)d_out;

    char* ws = (char*)d_ws;
    u32*   cnt     = (u32*)  (ws);                 //    800,000 B (4,NN)
    u32*   cnt2    = (u32*)  (ws + 800000);        //    800,000 B (4,NN)
    u32*   bsum    = (u32*)  (ws + 1600000);       //      4,096 B (4,256)
    u32*   row_ptr = (u32*)  (ws + 1604096);       //    800,016 B (4,NN+1)
    float* ra      = (float*)(ws + 2404112);       //      8,192 B (4,512)
    u16*   WcatS   = (u16*)  (ws + 2412304);       //  1,179,648 B (4,9,32,64,8) bf16
    float* e_comb  = (float*)(ws + 3591952);       // 12,800,000 B (4,NN,16) [src|dst]
    u32*   src_pack= (u32*)  (ws + 16391952);      //  3,200,000 B (4,NE)
    float* e_pack  = (float*)(ws + 19591952);      // 25,600,000 B (4,NE,8)
    u16*   fsrc    = (u16*)  (ws + 45191952);      //102,400,000 B (4,NN,256) bf16
    u16*   resb    = (u16*)  (ws + 147591952);     //102,400,000 B (4,NN,256) bf16
    // total: 249,991,952 B

    hipMemsetAsync(cnt, 0, 1604096, stream);  // cnt + cnt2 + bsum

    k_ra<<<4, 256, 0, stream>>>(rel_emb, rel_W, ra);
    k_wcat<<<(4*WCT*256)/256, 256, 0, stream>>>(node_W, res_W, ra, WcatS);
    dim3 gg((NN+127)/128, 4);
    k_gemm<<<gg, 512, 0, stream>>>(feat, WcatS, res_b, fsrc, resb, e_comb);

    dim3 geg((NE+255)/256, 4);
    k_count<<<geg, 256, 0, stream>>>(dst_idx, cnt);
    dim3 gsc((NN+255)/256, 4);
    k_scan1<<<gsc, 256, 0, stream>>>(cnt, bsum);
    k_scan2<<<4, 256, 0, stream>>>(bsum);
    k_scan3<<<gsc, 256, 0, stream>>>(cnt, bsum, row_ptr);
    k_scatter<<<geg, 256, 0, stream>>>(src_idx, dst_idx, e_comb, row_ptr, cnt2,
                                       src_pack, e_pack);
    k_agg12<<<NN, 128, 0, stream>>>(row_ptr, src_pack, e_pack, fsrc, resb,
                                    res_alpha, out);
    k_aggx03<<<NN, 128, 0, stream>>>(row_ptr, src_pack, e_pack, fsrc, resb,
                                     res_alpha, cross_attn, out);
    k_relout<<<4, 256, 0, stream>>>(rel_emb, prop_W, prop_b, out);
}